// Round 2
// baseline (32245.374 us; speedup 1.0000x reference)
//
#include <hip/hip_runtime.h>
#include <hip/hip_bf16.h>

// Qwen3.5 GatedDeltaNet: B=2, T=4096, D=2048, NV=32, NK=16, DK=DV=128, KC=4
// Round 2: same structure, workspace high-water cut 532 -> 228 MiB
// (suspected ws_size overflow caused round-1 device abort).

typedef __attribute__((ext_vector_type(8))) short short8;
typedef __attribute__((ext_vector_type(4))) float f32x4;

static __device__ __forceinline__ unsigned short f2b(float f) {
  __hip_bfloat16 h = __float2bfloat16(f);
  return __builtin_bit_cast(unsigned short, h);
}
static __device__ __forceinline__ float b2f(unsigned short u) {
  return __bfloat162float(__builtin_bit_cast(__hip_bfloat16, u));
}
static __device__ __forceinline__ unsigned pack2(float a, float b) {
  return (unsigned)f2b(a) | ((unsigned)f2b(b) << 16);
}

// ---------------- fp32 [K][N] -> bf16 [N][K] transpose-convert ----------------
__global__ __launch_bounds__(256) void transpose_cvt(const float* __restrict__ in,
    unsigned short* __restrict__ out, int K, int N, int row_off, int out_ld) {
  __shared__ float tile[32][33];
  int tx = threadIdx.x & 31, ty = threadIdx.x >> 5;
  int n0 = blockIdx.x * 32, k0 = blockIdx.y * 32;
#pragma unroll
  for (int r = 0; r < 4; ++r) {
    int kk = k0 + ty + r * 8, nn = n0 + tx;
    tile[ty + r * 8][tx] = (kk < K && nn < N) ? in[(size_t)kk * N + nn] : 0.f;
  }
  __syncthreads();
#pragma unroll
  for (int r = 0; r < 4; ++r) {
    int nn = n0 + ty + r * 8, kk = k0 + tx;
    if (nn < N && kk < K)
      out[(size_t)(nn + row_off) * out_ld + kk] = f2b(tile[tx][ty + r * 8]);
  }
}

// ---------------- bf16 TN GEMM: A[M][K] * B[N][K]^T -> C[M][N] ----------------
// 128x128 tile, 4 waves (2x2), 16x16x32 MFMA, BK=32.
// AF32: A is fp32, converted to bf16 during LDS staging.
template <bool BF16OUT, bool AF32>
__global__ __launch_bounds__(256) void gemm_tn(const void* __restrict__ Ap,
    const unsigned short* __restrict__ B, void* __restrict__ Cout,
    int M, int N, int K) {
  __shared__ unsigned short Ash[128][40];  // pad to 40 (80B stride): 2-way conflicts only
  __shared__ unsigned short Bsh[128][40];
  int tid = threadIdx.x;
  int bm = blockIdx.x * 128, bn = blockIdx.y * 128;
  int w = tid >> 6, lane = tid & 63;
  int wm = (w >> 1) * 64, wn = (w & 1) * 64;
  f32x4 acc[4][4] = {};
  for (int kt = 0; kt < K; kt += 32) {
#pragma unroll
    for (int it = 0; it < 2; ++it) {
      int idx = tid + it * 256;
      int row = idx >> 2, kc = idx & 3;
      uint4 av;
      if (AF32) {
        const float* Af = reinterpret_cast<const float*>(Ap);
        const float4* p = reinterpret_cast<const float4*>(Af + (size_t)(bm + row) * K + kt + kc * 8);
        float4 f0 = p[0], f1 = p[1];
        av.x = pack2(f0.x, f0.y); av.y = pack2(f0.z, f0.w);
        av.z = pack2(f1.x, f1.y); av.w = pack2(f1.z, f1.w);
      } else {
        const unsigned short* Ab = reinterpret_cast<const unsigned short*>(Ap);
        av = *reinterpret_cast<const uint4*>(Ab + (size_t)(bm + row) * K + kt + kc * 8);
      }
      *reinterpret_cast<uint4*>(&Ash[row][kc * 8]) = av;
      uint4 bv = make_uint4(0u, 0u, 0u, 0u);
      int col = bn + row;
      if (col < N)
        bv = *reinterpret_cast<const uint4*>(B + (size_t)col * K + kt + kc * 8);
      *reinterpret_cast<uint4*>(&Bsh[row][kc * 8]) = bv;
    }
    __syncthreads();
    short8 af[4], bf[4];
#pragma unroll
    for (int f = 0; f < 4; ++f) {
      af[f] = *reinterpret_cast<const short8*>(&Ash[wm + f * 16 + (lane & 15)][(lane >> 4) * 8]);
      bf[f] = *reinterpret_cast<const short8*>(&Bsh[wn + f * 16 + (lane & 15)][(lane >> 4) * 8]);
    }
#pragma unroll
    for (int i = 0; i < 4; ++i)
#pragma unroll
      for (int j = 0; j < 4; ++j)
        acc[i][j] = __builtin_amdgcn_mfma_f32_16x16x32_bf16(af[i], bf[j], acc[i][j], 0, 0, 0);
    __syncthreads();
  }
#pragma unroll
  for (int i = 0; i < 4; ++i) {
#pragma unroll
    for (int j = 0; j < 4; ++j) {
      int c0 = bn + wn + j * 16 + (lane & 15);
      if (c0 < N) {
#pragma unroll
        for (int e = 0; e < 4; ++e) {
          int r = bm + wm + i * 16 + (lane >> 4) * 4 + e;
          if (BF16OUT)
            reinterpret_cast<unsigned short*>(Cout)[(size_t)r * N + c0] = f2b(acc[i][j][e]);
          else
            reinterpret_cast<float*>(Cout)[(size_t)r * N + c0] = acc[i][j][e];
        }
      }
    }
  }
}

// ---------------- conv(KC=4) + silu + l2norm for q,k channels [0,4096) ----------------
// mixed: bf16 [B*T][4096]; one block (256 thr) per token.
__global__ __launch_bounds__(256) void conv_qk(const unsigned short* __restrict__ mixed,
    const float* __restrict__ cw, unsigned short* __restrict__ q,
    unsigned short* __restrict__ k) {
  int bt = blockIdx.x;
  int b = bt >> 12, t = bt & 4095;
  int tid = threadIdx.x;
  float x[16];
#pragma unroll
  for (int j = 0; j < 16; ++j) {
    int c = j * 256 + tid;
    float4 w4 = *reinterpret_cast<const float4*>(cw + (size_t)c * 4);
    const float wv[4] = {w4.x, w4.y, w4.z, w4.w};
    float acc = 0.f;
#pragma unroll
    for (int i = 0; i < 4; ++i) {
      int tt = t - 3 + i;
      if (tt >= 0)
        acc += b2f(mixed[((size_t)(b * 4096 + tt)) * 4096 + c]) * wv[i];
    }
    x[j] = acc / (1.f + __expf(-acc));  // silu
  }
  // l2norm over each 128-dim head: for fixed j, tid<128 -> head 2j, tid>=128 -> head 2j+1
  __shared__ float wsum[4][16];
  int wid = tid >> 6;
#pragma unroll
  for (int j = 0; j < 16; ++j) {
    float s2 = x[j] * x[j];
#pragma unroll
    for (int m = 1; m < 64; m <<= 1) s2 += __shfl_xor(s2, m, 64);
    if ((tid & 63) == 0) wsum[wid][j] = s2;
  }
  __syncthreads();
#pragma unroll
  for (int j = 0; j < 16; ++j) {
    int w0 = (tid >> 7) * 2;
    float rn = rsqrtf(wsum[w0][j] + wsum[w0 + 1][j] + 1e-6f);
    int c = j * 256 + tid;
    int head = c >> 7;  // 0..15 q, 16..31 k
    int d = c & 127;
    if (head < 16)
      q[((size_t)bt * 16 + head) * 128 + d] = f2b(x[j] * rn * 0.08838834764831845f);
    else
      k[((size_t)bt * 16 + (head - 16)) * 128 + d] = f2b(x[j] * rn);
  }
}

// ---------------- conv + silu for v channels (cw pre-offset by 4096 rows) ----------------
__global__ __launch_bounds__(256) void conv_v(const unsigned short* __restrict__ mixed,
    const float* __restrict__ cw, unsigned short* __restrict__ v) {
  int bt = blockIdx.x;
  int b = bt >> 12, t = bt & 4095;
  int tid = threadIdx.x;
#pragma unroll
  for (int j = 0; j < 16; ++j) {
    int c = j * 256 + tid;
    float4 w4 = *reinterpret_cast<const float4*>(cw + (size_t)c * 4);
    const float wv[4] = {w4.x, w4.y, w4.z, w4.w};
    float acc = 0.f;
#pragma unroll
    for (int i = 0; i < 4; ++i) {
      int tt = t - 3 + i;
      if (tt >= 0)
        acc += b2f(mixed[((size_t)(b * 4096 + tt)) * 4096 + c]) * wv[i];
    }
    float s = acc / (1.f + __expf(-acc));
    v[((size_t)bt * 32 + (c >> 7)) * 128 + (c & 127)] = f2b(s);
  }
}

// ---------------- gate/beta from ba GEMM output ----------------
__global__ __launch_bounds__(256) void gate_beta(const float* __restrict__ ba,
    const float* __restrict__ dt_bias, const float* __restrict__ A_log,
    float* __restrict__ g, float* __restrict__ beta) {
  int idx = blockIdx.x * 256 + threadIdx.x;  // (b*T+t)*32 + h
  int bt = idx >> 5, h = idx & 31;
  float bv = ba[(size_t)bt * 64 + h];
  float av = ba[(size_t)bt * 64 + 32 + h];
  beta[idx] = 1.f / (1.f + __expf(-bv));
  float xx = av + dt_bias[h];
  float sp = (xx > 20.f) ? xx : log1pf(__expf(xx));
  g[idx] = -__expf(A_log[h]) * sp;
}

// ---------------- naive gated delta-rule scan ----------------
// block = (b,h); 128 threads; thread owns V-column `lane`, state S[0..127] in regs.
__global__ __launch_bounds__(128, 1) void scan_naive(const unsigned short* __restrict__ q,
    const unsigned short* __restrict__ k, const unsigned short* __restrict__ v,
    const float* __restrict__ g, const float* __restrict__ beta,
    unsigned short* __restrict__ o) {
  int b = blockIdx.x >> 5, h = blockIdx.x & 31;
  int hk = h >> 1;  // NV/NK = 2 repeat
  int lane = threadIdx.x;
  float S[128];
#pragma unroll
  for (int i = 0; i < 128; ++i) S[i] = 0.f;
  for (int t = 0; t < 4096; ++t) {
    size_t bt = (size_t)b * 4096 + t;
    const unsigned short* kt = k + (bt * 16 + hk) * 128;
    const unsigned short* qt = q + (bt * 16 + hk) * 128;
    float vv = b2f(v[(bt * 32 + h) * 128 + lane]);
    float eg = __expf(g[bt * 32 + h]);
    float bb = beta[bt * 32 + h];
    float p0 = 0, p1 = 0, p2 = 0, p3 = 0;
#pragma unroll
    for (int i = 0; i < 128; i += 4) {
      p0 += b2f(kt[i]) * S[i];
      p1 += b2f(kt[i + 1]) * S[i + 1];
      p2 += b2f(kt[i + 2]) * S[i + 2];
      p3 += b2f(kt[i + 3]) * S[i + 3];
    }
    float delta = bb * (vv - ((p0 + p1) + (p2 + p3)) * eg);
    float o0 = 0, o1 = 0, o2 = 0, o3 = 0;
#pragma unroll
    for (int i = 0; i < 128; i += 4) {
      float s0 = S[i] * eg + b2f(kt[i]) * delta;       S[i] = s0;     o0 += b2f(qt[i]) * s0;
      float s1 = S[i + 1] * eg + b2f(kt[i + 1]) * delta; S[i + 1] = s1; o1 += b2f(qt[i + 1]) * s1;
      float s2 = S[i + 2] * eg + b2f(kt[i + 2]) * delta; S[i + 2] = s2; o2 += b2f(qt[i + 2]) * s2;
      float s3 = S[i + 3] * eg + b2f(kt[i + 3]) * delta; S[i + 3] = s3; o3 += b2f(qt[i + 3]) * s3;
    }
    o[(bt * 32 + h) * 128 + lane] = f2b((o0 + o1) + (o2 + o3));
  }
}

// ---------------- gated RMSNorm (bf16 o, bf16 z) -> bf16 y ----------------
__global__ __launch_bounds__(256) void rms_gate(const unsigned short* __restrict__ o,
    const unsigned short* __restrict__ z, const float* __restrict__ nw,
    unsigned short* __restrict__ y) {
  int wid = threadIdx.x >> 6, lane = threadIdx.x & 63;
  size_t base = ((size_t)blockIdx.x * 4 + wid) * 128;
  float o0 = b2f(o[base + lane]), o1 = b2f(o[base + lane + 64]);
  float ss = o0 * o0 + o1 * o1;
#pragma unroll
  for (int m = 1; m < 64; m <<= 1) ss += __shfl_xor(ss, m, 64);
  float r = rsqrtf(ss * (1.f / 128.f) + 1e-6f);
  float z0 = b2f(z[base + lane]), z1 = b2f(z[base + lane + 64]);
  z0 = z0 / (1.f + __expf(-z0));
  z1 = z1 / (1.f + __expf(-z1));
  y[base + lane] = f2b(o0 * r * nw[lane] * z0);
  y[base + lane + 64] = f2b(o1 * r * nw[lane + 64] * z1);
}

extern "C" void kernel_launch(void* const* d_in, const int* in_sizes, int n_in,
                              void* d_out, int out_size, void* d_ws, size_t ws_size,
                              hipStream_t stream) {
  const float* hs      = (const float*)d_in[0];
  const float* W_qkv   = (const float*)d_in[1];
  const float* W_z     = (const float*)d_in[2];
  const float* W_b     = (const float*)d_in[3];
  const float* W_a     = (const float*)d_in[4];
  const float* conv_w  = (const float*)d_in[5];
  const float* dt_bias = (const float*)d_in[6];
  const float* A_log   = (const float*)d_in[7];
  const float* norm_w  = (const float*)d_in[8];
  const float* W_out   = (const float*)d_in[9];
  float* out = (float*)d_out;

  char* ws = (char*)d_ws;
  const size_t MiB = 1u << 20;
  // layout (MiB), high-water 228:
  //   0-32   wt (weight^T staging: W_qkv^T 32 -> W_b/a^T -> W_z^T 16 -> W_out^T 16)
  //   32-96  mixed chunk (64) -> o bf16 (64) after convs
  //   96-128 q bf16 | 128-160 k bf16   -> z bf16 (64) after scan
  //   160-224 v bf16 -> y bf16 after scan
  //   224-226 ba | 226-227 g | 227-228 beta
  unsigned short* wt      = (unsigned short*)(ws);
  unsigned short* mixed_c = (unsigned short*)(ws + 32 * MiB);
  unsigned short* o_buf   = mixed_c;
  unsigned short* q_buf   = (unsigned short*)(ws + 96 * MiB);
  unsigned short* k_buf   = (unsigned short*)(ws + 128 * MiB);
  unsigned short* z_bf    = q_buf;
  unsigned short* v_buf   = (unsigned short*)(ws + 160 * MiB);
  unsigned short* y_bf    = v_buf;
  float*          ba_buf  = (float*)(ws + 224 * MiB);
  float*          g_buf   = (float*)(ws + 226 * MiB);
  float*          bt_buf  = (float*)(ws + 227 * MiB);

  // qkv projection, chunked over output channels (2 x 4096) + conv/norm
  transpose_cvt<<<dim3(256, 64), 256, 0, stream>>>(W_qkv, wt, 2048, 8192, 0, 2048);
  gemm_tn<true, true><<<dim3(64, 32), 256, 0, stream>>>(hs, wt, mixed_c, 8192, 4096, 2048);
  conv_qk<<<8192, 256, 0, stream>>>(mixed_c, conv_w, q_buf, k_buf);
  gemm_tn<true, true><<<dim3(64, 32), 256, 0, stream>>>(hs, wt + (size_t)4096 * 2048, mixed_c, 8192, 4096, 2048);
  conv_v<<<8192, 256, 0, stream>>>(mixed_c, conv_w + (size_t)4096 * 4, v_buf);
  // beta / a projections (64 cols), gates
  transpose_cvt<<<dim3(1, 64), 256, 0, stream>>>(W_b, wt, 2048, 32, 0, 2048);
  transpose_cvt<<<dim3(1, 64), 256, 0, stream>>>(W_a, wt, 2048, 32, 32, 2048);
  gemm_tn<false, true><<<dim3(64, 1), 256, 0, stream>>>(hs, wt, ba_buf, 8192, 64, 2048);
  gate_beta<<<1024, 256, 0, stream>>>(ba_buf, dt_bias, A_log, g_buf, bt_buf);
  // sequential gated delta-rule scan -> o (overwrites mixed chunk)
  scan_naive<<<64, 128, 0, stream>>>(q_buf, k_buf, v_buf, g_buf, bt_buf, o_buf);
  // z projection (into dead q/k region)
  transpose_cvt<<<dim3(128, 64), 256, 0, stream>>>(W_z, wt, 2048, 4096, 0, 2048);
  gemm_tn<true, true><<<dim3(64, 32), 256, 0, stream>>>(hs, wt, z_bf, 8192, 4096, 2048);
  // gated RMSNorm -> y (into dead v region)
  rms_gate<<<65536, 256, 0, stream>>>(o_buf, z_bf, norm_w, y_bf);
  // output projection
  transpose_cvt<<<dim3(64, 128), 256, 0, stream>>>(W_out, wt, 4096, 2048, 0, 4096);
  gemm_tn<false, false><<<dim3(64, 16), 256, 0, stream>>>(y_bf, wt, out, 8192, 2048, 4096);
}

// Round 3
// 2349.779 us; speedup vs baseline: 13.7227x; 13.7227x over previous
//
#include <hip/hip_runtime.h>
#include <hip/hip_bf16.h>

// Qwen3.5 GatedDeltaNet: B=2, T=4096, D=2048, NV=32, NK=16, DK=DV=128, KC=4
// Round 3: chunked delta-rule scan (C=64) — all-MFMA, T=(I+D)^-1 via nilpotent
// squaring chain. Replaces the 30.8ms serial scan.

typedef __attribute__((ext_vector_type(8))) short short8;
typedef __attribute__((ext_vector_type(4))) float f32x4;

static __device__ __forceinline__ unsigned short f2b(float f) {
  __hip_bfloat16 h = __float2bfloat16(f);
  return __builtin_bit_cast(unsigned short, h);
}
static __device__ __forceinline__ float b2f(unsigned short u) {
  return __bfloat162float(__builtin_bit_cast(__hip_bfloat16, u));
}
static __device__ __forceinline__ unsigned pack2(float a, float b) {
  return (unsigned)f2b(a) | ((unsigned)f2b(b) << 16);
}

// ---------------- fp32 [K][N] -> bf16 [N][K] transpose-convert ----------------
__global__ __launch_bounds__(256) void transpose_cvt(const float* __restrict__ in,
    unsigned short* __restrict__ out, int K, int N, int row_off, int out_ld) {
  __shared__ float tile[32][33];
  int tx = threadIdx.x & 31, ty = threadIdx.x >> 5;
  int n0 = blockIdx.x * 32, k0 = blockIdx.y * 32;
#pragma unroll
  for (int r = 0; r < 4; ++r) {
    int kk = k0 + ty + r * 8, nn = n0 + tx;
    tile[ty + r * 8][tx] = (kk < K && nn < N) ? in[(size_t)kk * N + nn] : 0.f;
  }
  __syncthreads();
#pragma unroll
  for (int r = 0; r < 4; ++r) {
    int nn = n0 + ty + r * 8, kk = k0 + tx;
    if (nn < N && kk < K)
      out[(size_t)(nn + row_off) * out_ld + kk] = f2b(tile[tx][ty + r * 8]);
  }
}

// ---------------- bf16 TN GEMM: A[M][K] * B[N][K]^T -> C[M][N] ----------------
template <bool BF16OUT, bool AF32>
__global__ __launch_bounds__(256) void gemm_tn(const void* __restrict__ Ap,
    const unsigned short* __restrict__ B, void* __restrict__ Cout,
    int M, int N, int K) {
  __shared__ unsigned short Ash[128][40];
  __shared__ unsigned short Bsh[128][40];
  int tid = threadIdx.x;
  int bm = blockIdx.x * 128, bn = blockIdx.y * 128;
  int w = tid >> 6, lane = tid & 63;
  int wm = (w >> 1) * 64, wn = (w & 1) * 64;
  f32x4 acc[4][4] = {};
  for (int kt = 0; kt < K; kt += 32) {
#pragma unroll
    for (int it = 0; it < 2; ++it) {
      int idx = tid + it * 256;
      int row = idx >> 2, kc = idx & 3;
      uint4 av;
      if (AF32) {
        const float* Af = reinterpret_cast<const float*>(Ap);
        const float4* p = reinterpret_cast<const float4*>(Af + (size_t)(bm + row) * K + kt + kc * 8);
        float4 f0 = p[0], f1 = p[1];
        av.x = pack2(f0.x, f0.y); av.y = pack2(f0.z, f0.w);
        av.z = pack2(f1.x, f1.y); av.w = pack2(f1.z, f1.w);
      } else {
        const unsigned short* Ab = reinterpret_cast<const unsigned short*>(Ap);
        av = *reinterpret_cast<const uint4*>(Ab + (size_t)(bm + row) * K + kt + kc * 8);
      }
      *reinterpret_cast<uint4*>(&Ash[row][kc * 8]) = av;
      uint4 bv = make_uint4(0u, 0u, 0u, 0u);
      int col = bn + row;
      if (col < N)
        bv = *reinterpret_cast<const uint4*>(B + (size_t)col * K + kt + kc * 8);
      *reinterpret_cast<uint4*>(&Bsh[row][kc * 8]) = bv;
    }
    __syncthreads();
    short8 af[4], bf[4];
#pragma unroll
    for (int f = 0; f < 4; ++f) {
      af[f] = *reinterpret_cast<const short8*>(&Ash[wm + f * 16 + (lane & 15)][(lane >> 4) * 8]);
      bf[f] = *reinterpret_cast<const short8*>(&Bsh[wn + f * 16 + (lane & 15)][(lane >> 4) * 8]);
    }
#pragma unroll
    for (int i = 0; i < 4; ++i)
#pragma unroll
      for (int j = 0; j < 4; ++j)
        acc[i][j] = __builtin_amdgcn_mfma_f32_16x16x32_bf16(af[i], bf[j], acc[i][j], 0, 0, 0);
    __syncthreads();
  }
#pragma unroll
  for (int i = 0; i < 4; ++i) {
#pragma unroll
    for (int j = 0; j < 4; ++j) {
      int c0 = bn + wn + j * 16 + (lane & 15);
      if (c0 < N) {
#pragma unroll
        for (int e = 0; e < 4; ++e) {
          int r = bm + wm + i * 16 + (lane >> 4) * 4 + e;
          if (BF16OUT)
            reinterpret_cast<unsigned short*>(Cout)[(size_t)r * N + c0] = f2b(acc[i][j][e]);
          else
            reinterpret_cast<float*>(Cout)[(size_t)r * N + c0] = acc[i][j][e];
        }
      }
    }
  }
}

// ---------------- conv(KC=4) + silu + l2norm for q,k channels ----------------
__global__ __launch_bounds__(256) void conv_qk(const unsigned short* __restrict__ mixed,
    const float* __restrict__ cw, unsigned short* __restrict__ q,
    unsigned short* __restrict__ k) {
  int bt = blockIdx.x;
  int b = bt >> 12, t = bt & 4095;
  int tid = threadIdx.x;
  float x[16];
#pragma unroll
  for (int j = 0; j < 16; ++j) {
    int c = j * 256 + tid;
    float4 w4 = *reinterpret_cast<const float4*>(cw + (size_t)c * 4);
    const float wv[4] = {w4.x, w4.y, w4.z, w4.w};
    float acc = 0.f;
#pragma unroll
    for (int i = 0; i < 4; ++i) {
      int tt = t - 3 + i;
      if (tt >= 0)
        acc += b2f(mixed[((size_t)(b * 4096 + tt)) * 4096 + c]) * wv[i];
    }
    x[j] = acc / (1.f + __expf(-acc));
  }
  __shared__ float wsum[4][16];
  int wid = tid >> 6;
#pragma unroll
  for (int j = 0; j < 16; ++j) {
    float s2 = x[j] * x[j];
#pragma unroll
    for (int m = 1; m < 64; m <<= 1) s2 += __shfl_xor(s2, m, 64);
    if ((tid & 63) == 0) wsum[wid][j] = s2;
  }
  __syncthreads();
#pragma unroll
  for (int j = 0; j < 16; ++j) {
    int w0 = (tid >> 7) * 2;
    float rn = rsqrtf(wsum[w0][j] + wsum[w0 + 1][j] + 1e-6f);
    int c = j * 256 + tid;
    int head = c >> 7;
    int d = c & 127;
    if (head < 16)
      q[((size_t)bt * 16 + head) * 128 + d] = f2b(x[j] * rn * 0.08838834764831845f);
    else
      k[((size_t)bt * 16 + (head - 16)) * 128 + d] = f2b(x[j] * rn);
  }
}

// ---------------- conv + silu for v channels ----------------
__global__ __launch_bounds__(256) void conv_v(const unsigned short* __restrict__ mixed,
    const float* __restrict__ cw, unsigned short* __restrict__ v) {
  int bt = blockIdx.x;
  int b = bt >> 12, t = bt & 4095;
  int tid = threadIdx.x;
#pragma unroll
  for (int j = 0; j < 16; ++j) {
    int c = j * 256 + tid;
    float4 w4 = *reinterpret_cast<const float4*>(cw + (size_t)c * 4);
    const float wv[4] = {w4.x, w4.y, w4.z, w4.w};
    float acc = 0.f;
#pragma unroll
    for (int i = 0; i < 4; ++i) {
      int tt = t - 3 + i;
      if (tt >= 0)
        acc += b2f(mixed[((size_t)(b * 4096 + tt)) * 4096 + c]) * wv[i];
    }
    float s = acc / (1.f + __expf(-acc));
    v[((size_t)bt * 32 + (c >> 7)) * 128 + (c & 127)] = f2b(s);
  }
}

// ---------------- gate/beta ----------------
__global__ __launch_bounds__(256) void gate_beta(const float* __restrict__ ba,
    const float* __restrict__ dt_bias, const float* __restrict__ A_log,
    float* __restrict__ g, float* __restrict__ beta) {
  int idx = blockIdx.x * 256 + threadIdx.x;
  int bt = idx >> 5, h = idx & 31;
  float bv = ba[(size_t)bt * 64 + h];
  float av = ba[(size_t)bt * 64 + 32 + h];
  beta[idx] = 1.f / (1.f + __expf(-bv));
  float xx = av + dt_bias[h];
  float sp = (xx > 20.f) ? xx : log1pf(__expf(xx));
  g[idx] = -__expf(A_log[h]) * sp;
}

// =======================================================================
// Chunked gated delta-rule scan. block = (b, h_v); 512 threads (8 waves).
// Chunk C=64. State S^T[v][d] bf16 in LDS, persistent across 64 chunks.
// =======================================================================
template <int KSTEPS>
static __device__ __forceinline__ f32x4 tile_tn(const unsigned short* As, int lda,
    const unsigned short* Bs, int ldb, int rt, int ct, int lane, f32x4 acc) {
  const unsigned short* ar = As + (rt * 16 + (lane & 15)) * lda + (lane >> 4) * 8;
  const unsigned short* br = Bs + (ct * 16 + (lane & 15)) * ldb + (lane >> 4) * 8;
#pragma unroll
  for (int ks = 0; ks < KSTEPS; ++ks) {
    short8 a = *reinterpret_cast<const short8*>(ar + ks * 32);
    short8 bb = *reinterpret_cast<const short8*>(br + ks * 32);
    acc = __builtin_amdgcn_mfma_f32_16x16x32_bf16(a, bb, acc, 0, 0, 0);
  }
  return acc;
}

__global__ __launch_bounds__(512, 1) void scan_chunked(
    const unsigned short* __restrict__ q, const unsigned short* __restrict__ k,
    const unsigned short* __restrict__ v, const float* __restrict__ g,
    const float* __restrict__ beta, unsigned short* __restrict__ o) {
  // strides (shorts): big=136 (272B rows), small=72 (144B rows): both 16B-aligned,
  // bank stride 4 words -> only 2-way conflicts (free).
  __shared__ unsigned short Sb[128 * 136];   // S^T [v][d]
  __shared__ unsigned short Kb[64 * 136];    // k row-major [t][d]
  __shared__ unsigned short KLu[128 * 72];   // phase1: KL=beta*e^b*k row-major(ld136,64rows); phase2: Kbar^T [d][t]
  __shared__ unsigned short Qb[64 * 136];    // q row-major; later scaled by e^{b_t}
  __shared__ unsigned short Vt[128 * 72];    // beta*V^T [v][t] -> RHS^T
  __shared__ unsigned short Ut[128 * 72];    // U^T [v][t]
  __shared__ unsigned short W1[64 * 72];     // E = D^(2^k)
  __shared__ unsigned short W1t[64 * 72];    // E^T
  __shared__ unsigned short W3[64 * 72];     // T
  __shared__ unsigned short WP[64 * 72];     // P
  __shared__ float bl[64], betl[64];

  int b = blockIdx.x >> 5, h = blockIdx.x & 31, hk = h >> 1;
  int tid = threadIdx.x, w = tid >> 6, lane = tid & 63;

  for (int i = tid; i < 128 * 136; i += 512) Sb[i] = 0;
  __syncthreads();

  for (int c = 0; c < 64; ++c) {
    size_t bt0 = (size_t)b * 4096 + c * 64;
    // ---- load chunk (regs) ----
    int row = tid >> 3, c16 = (tid & 7) * 16;
    const unsigned short* kp = k + ((bt0 + row) * 16 + hk) * 128 + c16;
    const unsigned short* qp = q + ((bt0 + row) * 16 + hk) * 128 + c16;
    const unsigned short* vp = v + ((bt0 + row) * 32 + h) * 128 + c16;
    uint4 kr0 = reinterpret_cast<const uint4*>(kp)[0];
    uint4 kr1 = reinterpret_cast<const uint4*>(kp)[1];
    uint4 qr0 = reinterpret_cast<const uint4*>(qp)[0];
    uint4 qr1 = reinterpret_cast<const uint4*>(qp)[1];
    uint4 vr0 = reinterpret_cast<const uint4*>(vp)[0];
    uint4 vr1 = reinterpret_cast<const uint4*>(vp)[1];
    if (tid < 64) {
      float x = g[(bt0 + tid) * 32 + h];
      float bv = beta[(bt0 + tid) * 32 + h];
#pragma unroll
      for (int off = 1; off < 64; off <<= 1) {
        float n = __shfl_up(x, off, 64);
        if (lane >= off) x += n;
      }
      bl[tid] = x;
      betl[tid] = bv;
    }
    __syncthreads();
    // ---- write LDS: Kb, KL, Qb, Vt ----
    {
      unsigned short kreg[16], qreg[16], vreg[16];
      *reinterpret_cast<uint4*>(kreg) = kr0; *reinterpret_cast<uint4*>(kreg + 8) = kr1;
      *reinterpret_cast<uint4*>(qreg) = qr0; *reinterpret_cast<uint4*>(qreg + 8) = qr1;
      *reinterpret_cast<uint4*>(vreg) = vr0; *reinterpret_cast<uint4*>(vreg + 8) = vr1;
      reinterpret_cast<uint4*>(&Kb[row * 136 + c16])[0] = kr0;
      reinterpret_cast<uint4*>(&Kb[row * 136 + c16])[1] = kr1;
      reinterpret_cast<uint4*>(&Qb[row * 136 + c16])[0] = qr0;
      reinterpret_cast<uint4*>(&Qb[row * 136 + c16])[1] = qr1;
      float bs = betl[row];
      float kls = bs * __expf(bl[row]);
      unsigned short klreg[16];
#pragma unroll
      for (int i = 0; i < 16; ++i) klreg[i] = f2b(kls * b2f(kreg[i]));
      reinterpret_cast<uint4*>(&KLu[row * 136 + c16])[0] = *reinterpret_cast<uint4*>(klreg);
      reinterpret_cast<uint4*>(&KLu[row * 136 + c16])[1] = *reinterpret_cast<uint4*>(klreg + 8);
#pragma unroll
      for (int i = 0; i < 16; ++i) Vt[(c16 + i) * 72 + row] = f2b(bs * b2f(vreg[i]));
    }
    __syncthreads();
    // ---- GEMM_A: D_raw (K K^T) rows by waves 0-3; P_raw (Q K^T) waves 4-7 ----
    {
      bool isP = w >= 4;
      int art = w & 3;
      const unsigned short* Arows = isP ? Qb : Kb;
#pragma unroll
      for (int ct = 0; ct < 4; ++ct) {
        f32x4 acc = tile_tn<4>(Arows, 136, Kb, 136, art, ct, lane, f32x4{});
        int col = ct * 16 + (lane & 15);
#pragma unroll
        for (int e = 0; e < 4; ++e) {
          int trow = art * 16 + (lane >> 4) * 4 + e;
          if (!isP) {
            float dv = (col < trow) ? betl[trow] * __expf(bl[trow] - bl[col]) * acc[e] : 0.f;
            W1[trow * 72 + col] = f2b(dv);
            W1t[col * 72 + trow] = f2b(dv);
            W3[trow * 72 + col] = f2b((trow == col ? 1.f : 0.f) - dv);
          } else {
            float pv = (col <= trow) ? __expf(bl[trow] - bl[col]) * acc[e] : 0.f;
            WP[trow * 72 + col] = f2b(pv);
          }
        }
      }
    }
    __syncthreads();
    // ---- RHS-GEMM: acc[v][t] = Sb . KL^T; Vt <- Vt - acc (in place) ----
    {
#pragma unroll
      for (int ct = 0; ct < 4; ++ct) {
        f32x4 acc = tile_tn<4>(Sb, 136, KLu, 136, w, ct, lane, f32x4{});
#pragma unroll
        for (int e = 0; e < 4; ++e) {
          int vv = w * 16 + (lane >> 4) * 4 + e, tt = ct * 16 + (lane & 15);
          Vt[vv * 72 + tt] = f2b(b2f(Vt[vv * 72 + tt]) - acc[e]);
        }
      }
    }
    __syncthreads();
    // ---- fills: Qb *= e^{b_t} (in place); KLu -> Kbar^T [d][t] ----
    for (int e = tid; e < 64 * 128; e += 512) {
      int tt = e >> 7, d = e & 127;
      Qb[tt * 136 + d] = f2b(b2f(Qb[tt * 136 + d]) * __expf(bl[tt]));
    }
    __syncthreads();  // KL reads done (RHS barrier) + ensure no overlap with writes below
    {
      float bC = bl[63];
      for (int e = tid; e < 64 * 128; e += 512) {
        int tt = e & 63, d = e >> 6;
        KLu[d * 72 + tt] = f2b(__expf(bC - bl[tt]) * b2f(Kb[tt * 136 + d]));
      }
    }
    __syncthreads();
    // ---- T-chain: T=(I-D)(I+D^2)(I+D^4)(I+D^8)(I+D^16)(I+D^32) ----
#pragma unroll
    for (int it = 1; it <= 5; ++it) {
      int pw = 1 << it;
      int rt = (w + 0 * 8) >> 2;  // tiles w and w+8
      f32x4 aE[2];
#pragma unroll
      for (int u2 = 0; u2 < 2; ++u2) {
        int tix = w + u2 * 8, r = tix >> 2, ctl = tix & 3;
        aE[u2] = f32x4{};
        if (r >= ctl && (r * 16 + 15 - ctl * 16) >= pw)
          aE[u2] = tile_tn<2>(W1, 72, W1t, 72, r, ctl, lane, aE[u2]);
      }
      __syncthreads();
#pragma unroll
      for (int u2 = 0; u2 < 2; ++u2) {
        int tix = w + u2 * 8, r = tix >> 2, ctl = tix & 3;
#pragma unroll
        for (int e = 0; e < 4; ++e) {
          int rr = r * 16 + (lane >> 4) * 4 + e, cc = ctl * 16 + (lane & 15);
          W1[rr * 72 + cc] = f2b(aE[u2][e]);
          W1t[cc * 72 + rr] = f2b(aE[u2][e]);
        }
      }
      __syncthreads();
      f32x4 aT[2];
#pragma unroll
      for (int u2 = 0; u2 < 2; ++u2) {
        int tix = w + u2 * 8, r = tix >> 2, ctl = tix & 3;
        aT[u2] = f32x4{};
        if (r >= ctl && (r * 16 + 15 - ctl * 16) >= pw)
          aT[u2] = tile_tn<2>(W3, 72, W1t, 72, r, ctl, lane, aT[u2]);
      }
      __syncthreads();
#pragma unroll
      for (int u2 = 0; u2 < 2; ++u2) {
        int tix = w + u2 * 8, r = tix >> 2, ctl = tix & 3;
#pragma unroll
        for (int e = 0; e < 4; ++e) {
          int rr = r * 16 + (lane >> 4) * 4 + e, cc = ctl * 16 + (lane & 15);
          W3[rr * 72 + cc] = f2b(b2f(W3[rr * 72 + cc]) + aT[u2][e]);
        }
      }
      __syncthreads();
      (void)rt;
    }
    // ---- U-GEMM: Ut[v][t] = RHS^T . T^T ----
    {
#pragma unroll
      for (int ct = 0; ct < 4; ++ct) {
        f32x4 acc = tile_tn<2>(Vt, 72, W3, 72, w, ct, lane, f32x4{});
#pragma unroll
        for (int e = 0; e < 4; ++e)
          Ut[(w * 16 + (lane >> 4) * 4 + e) * 72 + ct * 16 + (lane & 15)] = f2b(acc[e]);
      }
    }
    __syncthreads();
    // ---- O-GEMM: O[t][v] = (e^b Q).S0 + P.U ; write to global ----
    {
      int rt4 = w >> 1, cb = (w & 1) * 4;
#pragma unroll
      for (int cc4 = 0; cc4 < 4; ++cc4) {
        int ct = cb + cc4;
        f32x4 acc = tile_tn<4>(Qb, 136, Sb, 136, rt4, ct, lane, f32x4{});
        acc = tile_tn<2>(WP, 72, Ut, 72, rt4, ct, lane, acc);
        int vv = ct * 16 + (lane & 15);
#pragma unroll
        for (int e = 0; e < 4; ++e) {
          int tt = rt4 * 16 + (lane >> 4) * 4 + e;
          o[((bt0 + tt) * 32 + h) * 128 + vv] = f2b(acc[e]);
        }
      }
    }
    __syncthreads();
    // ---- S-update: Sb[v][d] = e^{b_C}*Sb + U^T.Kbar ----
    {
      float lamC = __expf(bl[63]);
#pragma unroll
      for (int ct = 0; ct < 8; ++ct) {
        f32x4 acc = tile_tn<2>(Ut, 72, KLu, 72, w, ct, lane, f32x4{});
#pragma unroll
        for (int e = 0; e < 4; ++e) {
          int vv = w * 16 + (lane >> 4) * 4 + e, dd = ct * 16 + (lane & 15);
          Sb[vv * 136 + dd] = f2b(lamC * b2f(Sb[vv * 136 + dd]) + acc[e]);
        }
      }
    }
    __syncthreads();
  }
}

// ---------------- gated RMSNorm ----------------
__global__ __launch_bounds__(256) void rms_gate(const unsigned short* __restrict__ o,
    const unsigned short* __restrict__ z, const float* __restrict__ nw,
    unsigned short* __restrict__ y) {
  int wid = threadIdx.x >> 6, lane = threadIdx.x & 63;
  size_t base = ((size_t)blockIdx.x * 4 + wid) * 128;
  float o0 = b2f(o[base + lane]), o1 = b2f(o[base + lane + 64]);
  float ss = o0 * o0 + o1 * o1;
#pragma unroll
  for (int m = 1; m < 64; m <<= 1) ss += __shfl_xor(ss, m, 64);
  float r = rsqrtf(ss * (1.f / 128.f) + 1e-6f);
  float z0 = b2f(z[base + lane]), z1 = b2f(z[base + lane + 64]);
  z0 = z0 / (1.f + __expf(-z0));
  z1 = z1 / (1.f + __expf(-z1));
  y[base + lane] = f2b(o0 * r * nw[lane] * z0);
  y[base + lane + 64] = f2b(o1 * r * nw[lane + 64] * z1);
}

extern "C" void kernel_launch(void* const* d_in, const int* in_sizes, int n_in,
                              void* d_out, int out_size, void* d_ws, size_t ws_size,
                              hipStream_t stream) {
  const float* hs      = (const float*)d_in[0];
  const float* W_qkv   = (const float*)d_in[1];
  const float* W_z     = (const float*)d_in[2];
  const float* W_b     = (const float*)d_in[3];
  const float* W_a     = (const float*)d_in[4];
  const float* conv_w  = (const float*)d_in[5];
  const float* dt_bias = (const float*)d_in[6];
  const float* A_log   = (const float*)d_in[7];
  const float* norm_w  = (const float*)d_in[8];
  const float* W_out   = (const float*)d_in[9];
  float* out = (float*)d_out;

  char* ws = (char*)d_ws;
  const size_t MiB = 1u << 20;
  unsigned short* wt      = (unsigned short*)(ws);
  unsigned short* mixed_c = (unsigned short*)(ws + 32 * MiB);
  unsigned short* o_buf   = mixed_c;
  unsigned short* q_buf   = (unsigned short*)(ws + 96 * MiB);
  unsigned short* k_buf   = (unsigned short*)(ws + 128 * MiB);
  unsigned short* z_bf    = q_buf;
  unsigned short* v_buf   = (unsigned short*)(ws + 160 * MiB);
  unsigned short* y_bf    = v_buf;
  float*          ba_buf  = (float*)(ws + 224 * MiB);
  float*          g_buf   = (float*)(ws + 226 * MiB);
  float*          bt_buf  = (float*)(ws + 227 * MiB);

  transpose_cvt<<<dim3(256, 64), 256, 0, stream>>>(W_qkv, wt, 2048, 8192, 0, 2048);
  gemm_tn<true, true><<<dim3(64, 32), 256, 0, stream>>>(hs, wt, mixed_c, 8192, 4096, 2048);
  conv_qk<<<8192, 256, 0, stream>>>(mixed_c, conv_w, q_buf, k_buf);
  gemm_tn<true, true><<<dim3(64, 32), 256, 0, stream>>>(hs, wt + (size_t)4096 * 2048, mixed_c, 8192, 4096, 2048);
  conv_v<<<8192, 256, 0, stream>>>(mixed_c, conv_w + (size_t)4096 * 4, v_buf);
  transpose_cvt<<<dim3(1, 64), 256, 0, stream>>>(W_b, wt, 2048, 32, 0, 2048);
  transpose_cvt<<<dim3(1, 64), 256, 0, stream>>>(W_a, wt, 2048, 32, 32, 2048);
  gemm_tn<false, true><<<dim3(64, 1), 256, 0, stream>>>(hs, wt, ba_buf, 8192, 64, 2048);
  gate_beta<<<1024, 256, 0, stream>>>(ba_buf, dt_bias, A_log, g_buf, bt_buf);
  // chunked delta-rule scan -> o (overwrites mixed region)
  scan_chunked<<<64, 512, 0, stream>>>(q_buf, k_buf, v_buf, g_buf, bt_buf, o_buf);
  transpose_cvt<<<dim3(128, 64), 256, 0, stream>>>(W_z, wt, 2048, 4096, 0, 2048);
  gemm_tn<true, true><<<dim3(64, 32), 256, 0, stream>>>(hs, wt, z_bf, 8192, 4096, 2048);
  rms_gate<<<65536, 256, 0, stream>>>(o_buf, z_bf, norm_w, y_bf);
  transpose_cvt<<<dim3(64, 128), 256, 0, stream>>>(W_out, wt, 4096, 2048, 0, 4096);
  gemm_tn<false, false><<<dim3(64, 16), 256, 0, stream>>>(y_bf, wt, out, 8192, 2048, 4096);
}

// Round 5
// 2084.324 us; speedup vs baseline: 15.4704x; 1.1274x over previous
//
#include <hip/hip_runtime.h>
#include <hip/hip_bf16.h>

// Qwen3.5 GatedDeltaNet: B=2, T=4096, D=2048, NV=32, NK=16, DK=DV=128, KC=4
// Round 5: fix ws overflow (z was 64 MiB, overran 236->268; now peak 172 MiB via
// scan-then-z ordering + hs_bf regen + in-place rms_gate) and fix T-chain math
// (round-4 used old-E factors => I - D^32; now correct (I+D)^-1 ping-pong chain).

typedef __attribute__((ext_vector_type(8))) short short8;
typedef __attribute__((ext_vector_type(4))) float f32x4;
typedef unsigned short us;

static __device__ __forceinline__ us f2b(float f) {
  __hip_bfloat16 h = __float2bfloat16(f);
  return __builtin_bit_cast(us, h);
}
static __device__ __forceinline__ float b2f(us u) {
  return __bfloat162float(__builtin_bit_cast(__hip_bfloat16, u));
}

// ---------------- fp32 -> bf16 elementwise ----------------
__global__ __launch_bounds__(256) void cvt_f32_bf16(const float* __restrict__ in,
    us* __restrict__ out, long n4) {
  long i = (long)blockIdx.x * 256 + threadIdx.x;
  long stride = (long)gridDim.x * 256;
  for (; i < n4; i += stride) {
    float4 f = reinterpret_cast<const float4*>(in)[i];
    ushort4 u;
    u.x = f2b(f.x); u.y = f2b(f.y); u.z = f2b(f.z); u.w = f2b(f.w);
    reinterpret_cast<ushort4*>(out)[i] = u;
  }
}

// ------- fp32 [K][Nfull] (col slice) -> bf16 [N][K] transpose-convert -------
__global__ __launch_bounds__(256) void transpose_cvt(const float* __restrict__ in,
    us* __restrict__ out, int K, int N, int Nfull, int coloff, int row_off) {
  __shared__ float tile[32][33];
  int tx = threadIdx.x & 31, ty = threadIdx.x >> 5;
  int n0 = blockIdx.x * 32, k0 = blockIdx.y * 32;
#pragma unroll
  for (int r = 0; r < 4; ++r) {
    int kk = k0 + ty + r * 8, nn = n0 + tx;
    tile[ty + r * 8][tx] = (kk < K && nn < N) ? in[(size_t)kk * Nfull + coloff + nn] : 0.f;
  }
  __syncthreads();
#pragma unroll
  for (int r = 0; r < 4; ++r) {
    int nn = n0 + ty + r * 8, kk = k0 + tx;
    if (nn < N && kk < K)
      out[(size_t)(nn + row_off) * K + kk] = f2b(tile[tx][ty + r * 8]);
  }
}

// ---------------- bf16 TN GEMM with global_load_lds staging ----------------
// A[M][K] * B[Nrows][K]^T -> C[M][*], 128x128 tile, 4 waves, BK=32.
// LDS linear [128][32] shorts; slot swizzle: phys = logical ^ ((row>>1)&3).
template <bool BF16OUT>
__global__ __launch_bounds__(256) void gemm_lds(const us* __restrict__ A,
    const us* __restrict__ B, void* __restrict__ Cout,
    int K, int Nb1, int Nvalid, int ldC, int coloff) {
  __shared__ us Ash[128 * 32];
  __shared__ us Bsh[128 * 32];
  int tid = threadIdx.x, w = tid >> 6, lane = tid & 63;
  int bm = blockIdx.x * 128, bn = blockIdx.y * 128;
  int wm = (w >> 1) * 64, wn = (w & 1) * 64;
  int r0 = w * 16 + (lane >> 2);
  int sx = ((lane & 3) ^ ((r0 >> 1) & 3)) * 8;
  const us* a0 = A + (size_t)(bm + r0) * K + sx;
  const us* a1 = a0 + (size_t)64 * K;
  int rb0 = bn + r0; if (rb0 > Nb1) rb0 = Nb1;
  int rb1 = bn + r0 + 64; if (rb1 > Nb1) rb1 = Nb1;
  const us* b0 = B + (size_t)rb0 * K + sx;
  const us* b1 = B + (size_t)rb1 * K + sx;
  us* lA0 = &Ash[w * 512]; us* lA1 = &Ash[2048 + w * 512];
  us* lB0 = &Bsh[w * 512]; us* lB1 = &Bsh[2048 + w * 512];
  f32x4 acc[4][4] = {};
  for (int kt = 0; kt < K; kt += 32) {
    __builtin_amdgcn_global_load_lds((const void*)(a0 + kt), (void*)lA0, 16, 0, 0);
    __builtin_amdgcn_global_load_lds((const void*)(a1 + kt), (void*)lA1, 16, 0, 0);
    __builtin_amdgcn_global_load_lds((const void*)(b0 + kt), (void*)lB0, 16, 0, 0);
    __builtin_amdgcn_global_load_lds((const void*)(b1 + kt), (void*)lB1, 16, 0, 0);
    __syncthreads();
    short8 af[4], bfr[4];
    int fr = lane & 15, j = lane >> 4;
#pragma unroll
    for (int f = 0; f < 4; ++f) {
      int Ra = wm + f * 16 + fr;
      af[f] = *reinterpret_cast<const short8*>(&Ash[Ra * 32 + ((j ^ ((Ra >> 1) & 3)) * 8)]);
      int Rb = wn + f * 16 + fr;
      bfr[f] = *reinterpret_cast<const short8*>(&Bsh[Rb * 32 + ((j ^ ((Rb >> 1) & 3)) * 8)]);
    }
#pragma unroll
    for (int i = 0; i < 4; ++i)
#pragma unroll
      for (int jj = 0; jj < 4; ++jj)
        acc[i][jj] = __builtin_amdgcn_mfma_f32_16x16x32_bf16(af[i], bfr[jj], acc[i][jj], 0, 0, 0);
    __syncthreads();
  }
#pragma unroll
  for (int i = 0; i < 4; ++i)
#pragma unroll
    for (int jj = 0; jj < 4; ++jj) {
      int c0 = bn + wn + jj * 16 + (lane & 15);
      if (c0 < Nvalid) {
#pragma unroll
        for (int e = 0; e < 4; ++e) {
          int r = bm + wm + i * 16 + (lane >> 4) * 4 + e;
          size_t off = (size_t)r * ldC + coloff + c0;
          if (BF16OUT) reinterpret_cast<us*>(Cout)[off] = f2b(acc[i][jj][e]);
          else reinterpret_cast<float*>(Cout)[off] = acc[i][jj][e];
        }
      }
    }
}

// -------- conv(KC=4)+silu (+l2norm) on a 2048-channel chunk --------
// MODE 0: q (l2norm * DK^-0.5), 1: k (l2norm), 2: v (silu only)
template <int MODE>
__global__ __launch_bounds__(256) void conv_chunk(const us* __restrict__ mixed,
    const float* __restrict__ cw, us* __restrict__ outp, int headbase) {
  int bt = blockIdx.x, b = bt >> 12, t = bt & 4095, tid = threadIdx.x;
  float x[8];
#pragma unroll
  for (int jj = 0; jj < 8; ++jj) {
    int c = jj * 256 + tid;
    float4 w4 = *reinterpret_cast<const float4*>(cw + (size_t)c * 4);
    float wv[4] = {w4.x, w4.y, w4.z, w4.w};
    float acc = 0.f;
#pragma unroll
    for (int i = 0; i < 4; ++i) {
      int tt = t - 3 + i;
      if (tt >= 0) acc += b2f(mixed[((size_t)(b * 4096 + tt)) * 2048 + c]) * wv[i];
    }
    x[jj] = acc / (1.f + __expf(-acc));
  }
  if (MODE < 2) {
    __shared__ float wsum[4][8];
    int wid = tid >> 6;
#pragma unroll
    for (int jj = 0; jj < 8; ++jj) {
      float s2 = x[jj] * x[jj];
#pragma unroll
      for (int m = 1; m < 64; m <<= 1) s2 += __shfl_xor(s2, m, 64);
      if ((tid & 63) == 0) wsum[wid][jj] = s2;
    }
    __syncthreads();
#pragma unroll
    for (int jj = 0; jj < 8; ++jj) {
      int w0 = (tid >> 7) * 2;
      float rn = rsqrtf(wsum[w0][jj] + wsum[w0 + 1][jj] + 1e-6f);
      int c = jj * 256 + tid;
      float val = x[jj] * rn * (MODE == 0 ? 0.08838834764831845f : 1.f);
      outp[((size_t)bt * 16 + (c >> 7)) * 128 + (c & 127)] = f2b(val);
    }
  } else {
#pragma unroll
    for (int jj = 0; jj < 8; ++jj) {
      int c = jj * 256 + tid;
      outp[((size_t)bt * 32 + headbase + (c >> 7)) * 128 + (c & 127)] = f2b(x[jj]);
    }
  }
}

// -------- gates: beta/g from ba, cumsum g within chunks of 64 --------
__global__ __launch_bounds__(256) void gates_cumsum(const float* __restrict__ ba,
    const float* __restrict__ dt_bias, const float* __restrict__ A_log,
    float* __restrict__ bl_g, float* __restrict__ beta_g) {
  int widx = blockIdx.x * 4 + (threadIdx.x >> 6);  // (b*32+h)*64 + chunk
  int lane = threadIdx.x & 63;
  int bh = widx >> 6, chunk = widx & 63;
  int b = bh >> 5, h = bh & 31;
  size_t btl = (size_t)b * 4096 + chunk * 64 + lane;
  float bv = ba[btl * 64 + h];
  float av = ba[btl * 64 + 32 + h];
  float beta = 1.f / (1.f + __expf(-bv));
  float xx = av + dt_bias[h];
  float sp = (xx > 20.f) ? xx : log1pf(__expf(xx));
  float g = -__expf(A_log[h]) * sp;
#pragma unroll
  for (int off = 1; off < 64; off <<= 1) {
    float n = __shfl_up(g, off, 64);
    if (lane >= off) g += n;
  }
  bl_g[(size_t)widx * 64 + lane] = g;
  beta_g[(size_t)widx * 64 + lane] = beta;
}

// =======================================================================
// Chunked gated delta-rule scan (corrected T-chain, 15 barriers/chunk).
// =======================================================================
static __device__ __forceinline__ f32x4 tile_range(const us* A, int lda,
    const us* B, int ldb, int rt, int ct, int l0, int nk, int lane, f32x4 acc) {
  const us* ar = A + (rt * 16 + (lane & 15)) * lda + l0 * 16 + (lane >> 4) * 8;
  const us* br = B + (ct * 16 + (lane & 15)) * ldb + l0 * 16 + (lane >> 4) * 8;
#pragma unroll
  for (int ks = 0; ks < nk; ++ks) {
    short8 a = *reinterpret_cast<const short8*>(ar + ks * 32);
    short8 bb = *reinterpret_cast<const short8*>(br + ks * 32);
    acc = __builtin_amdgcn_mfma_f32_16x16x32_bf16(a, bb, acc, 0, 0, 0);
  }
  return acc;
}

__global__ __launch_bounds__(512, 1) void scan2(
    const us* __restrict__ q, const us* __restrict__ k, const us* __restrict__ v,
    const float* __restrict__ bl_g, const float* __restrict__ beta_g,
    us* __restrict__ o) {
  __shared__ us Sb[128 * 136];    // S^T [v][d], persistent
  __shared__ us KbE[64 * 136];    // Kb [t][d]  /  E ping (Eb, ld 72)
  __shared__ us QbEt[64 * 136];   // Qb [t][d]  /  E^T ping (Ebt, ld 72)
  __shared__ us Ktb[128 * 72];    // e^{bC-b_t} K^T [d][t]
  __shared__ us Vt[128 * 72];     // RHS^T [v][t]
  __shared__ us Ut[128 * 72];     // U^T [v][t]
  __shared__ us W1[64 * 72], W1t[64 * 72], W3[64 * 72], WP[64 * 72];
  __shared__ float bl_s[64], bet_s[64];
  us* const Kb = KbE;  us* const Eb = KbE;
  us* const Qb = QbEt; us* const Ebt = QbEt;

  int bh = blockIdx.x, b = bh >> 5, h = bh & 31, hk = h >> 1;
  int tid = threadIdx.x, w = tid >> 6, lane = tid & 63;
  int row = tid >> 3, c16 = (tid & 7) * 16;

  for (int i = tid; i < (128 * 136) / 8; i += 512)
    reinterpret_cast<uint4*>(Sb)[i] = make_uint4(0, 0, 0, 0);
  __syncthreads();

  const int TR_[10] = {0, 1, 1, 2, 2, 2, 3, 3, 3, 3};
  const int TC_[10] = {0, 0, 1, 0, 1, 2, 0, 1, 2, 3};

  for (int c = 0; c < 64; ++c) {
    size_t bt0 = (size_t)b * 4096 + c * 64;
    // ---------------- LF: load + fill ----------------
    const us* kp = k + ((bt0 + row) * 16 + hk) * 128 + c16;
    const us* qp = q + ((bt0 + row) * 16 + hk) * 128 + c16;
    const us* vp = v + ((bt0 + row) * 32 + h) * 128 + c16;
    uint4 kr0 = reinterpret_cast<const uint4*>(kp)[0];
    uint4 kr1 = reinterpret_cast<const uint4*>(kp)[1];
    uint4 qr0 = reinterpret_cast<const uint4*>(qp)[0];
    uint4 qr1 = reinterpret_cast<const uint4*>(qp)[1];
    uint4 vr0 = reinterpret_cast<const uint4*>(vp)[0];
    uint4 vr1 = reinterpret_cast<const uint4*>(vp)[1];
    int gbase = (bh * 64 + c) * 64;
    float blr = bl_g[gbase + row], blC = bl_g[gbase + 63];
    float bet = beta_g[gbase + row];
    if ((tid & 7) == 0) { bl_s[row] = blr; bet_s[row] = bet; }
    *reinterpret_cast<uint4*>(&Kb[row * 136 + c16]) = kr0;
    *reinterpret_cast<uint4*>(&Kb[row * 136 + c16 + 8]) = kr1;
    *reinterpret_cast<uint4*>(&Qb[row * 136 + c16]) = qr0;
    *reinterpret_cast<uint4*>(&Qb[row * 136 + c16 + 8]) = qr1;
    us kreg[16], vreg[16];
    *reinterpret_cast<uint4*>(kreg) = kr0; *reinterpret_cast<uint4*>(kreg + 8) = kr1;
    *reinterpret_cast<uint4*>(vreg) = vr0; *reinterpret_cast<uint4*>(vreg + 8) = vr1;
    float ksc = __expf(blC - blr);
#pragma unroll
    for (int i = 0; i < 16; ++i) Ktb[(c16 + i) * 72 + row] = f2b(ksc * b2f(kreg[i]));
#pragma unroll
    for (int i = 0; i < 16; ++i) Vt[(c16 + i) * 72 + row] = f2b(bet * b2f(vreg[i]));
    __syncthreads();
    // ---------------- DPRO: D,P + Q.S0(regs) + RHS ----------------
    f32x4 o1[4];
    int rtO = w >> 1, cbO = (w & 1) * 4;
#pragma unroll
    for (int cc = 0; cc < 4; ++cc)
      o1[cc] = tile_range(Qb, 136, Sb, 136, rtO, cbO + cc, 0, 4, lane, f32x4{});
    {
      int art = w & 3;
      const us* Ar = (w < 4) ? Kb : Qb;
#pragma unroll
      for (int ct4 = 0; ct4 < 4; ++ct4) {
        f32x4 a = tile_range(Ar, 136, Kb, 136, art, ct4, 0, 4, lane, f32x4{});
#pragma unroll
        for (int e = 0; e < 4; ++e) {
          int tr = art * 16 + (lane >> 4) * 4 + e;
          int cl = ct4 * 16 + (lane & 15);
          if (w < 4) {
            float dv = (cl < tr) ? bet_s[tr] * __expf(bl_s[tr] - bl_s[cl]) * a[e] : 0.f;
            W1[tr * 72 + cl] = f2b(dv);
            W1t[cl * 72 + tr] = f2b(dv);
            W3[tr * 72 + cl] = f2b((tr == cl ? 1.f : 0.f) - dv);
          } else {
            float pv = (cl <= tr) ? __expf(bl_s[tr] - bl_s[cl]) * a[e] : 0.f;
            WP[tr * 72 + cl] = f2b(pv);
          }
        }
      }
    }
#pragma unroll
    for (int ct4 = 0; ct4 < 4; ++ct4) {
      f32x4 a = tile_range(Sb, 136, Kb, 136, w, ct4, 0, 4, lane, f32x4{});
      int tt = ct4 * 16 + (lane & 15);
      float csc = bet_s[tt] * __expf(bl_s[tt]);
#pragma unroll
      for (int e = 0; e < 4; ++e) {
        int vv = w * 16 + (lane >> 4) * 4 + e;
        Vt[vv * 72 + tt] = f2b(b2f(Vt[vv * 72 + tt]) - csc * a[e]);
      }
    }
    __syncthreads();
    // ------- T-chain: T=(I+D)^-1 = (I-D)(I+D^2)(I+D^4)(I+D^8)(I+D^16)(I+D^32) -------
    // ping-pong: odd it: square W1->Eb; even it: square Eb->W1.
    // phase A: W3 += F_prev (regs) + square; phase B: F = W3 . E_new (regs).
    f32x4 freg[2] = {};
#pragma unroll
    for (int it = 1; it <= 5; ++it) {
      if (it > 1) {
#pragma unroll
        for (int s = 0; s < 2; ++s) {
          int j = w + s * 8;
          if (j < 10) {
            int r = TR_[j], cc0 = TC_[j];
#pragma unroll
            for (int e = 0; e < 4; ++e) {
              int rr = r * 16 + (lane >> 4) * 4 + e, cl = cc0 * 16 + (lane & 15);
              W3[rr * 72 + cl] = f2b(b2f(W3[rr * 72 + cl]) + freg[s][e]);
            }
          }
        }
      }
      if (it == 1) {  // zero stale complements of Eb (upper) / Ebt (lower), once per chunk
        const int ZR[12] = {0, 0, 0, 1, 1, 2, 1, 2, 2, 3, 3, 3};
        const int ZC[12] = {1, 2, 3, 2, 3, 3, 0, 0, 1, 0, 1, 2};
#pragma unroll
        for (int u = 0; u < 12; ++u) {
          if ((u & 7) != w) continue;
          us* arr = (u < 6) ? Eb : Ebt;
          if (lane < 32) {
            int rr = ZR[u] * 16 + (lane >> 1);
            *reinterpret_cast<uint4*>(&arr[rr * 72 + ZC[u] * 16 + (lane & 1) * 8]) =
                make_uint4(0, 0, 0, 0);
          }
        }
      }
      const us* Es  = (it & 1) ? W1  : Eb;
      const us* Est = (it & 1) ? W1t : Ebt;
      us* Ed  = (it & 1) ? Eb  : W1;
      us* Edt = (it & 1) ? Ebt : W1t;
#pragma unroll
      for (int s = 0; s < 2; ++s) {
        int j = w + s * 8;
        if (j < 10) {
          int r = TR_[j], cc0 = TC_[j];
          int l0 = cc0 & ~1, nk = (r - l0 + 2) >> 1;
          f32x4 a = tile_range(Es, 72, Est, 72, r, cc0, l0, nk, lane, f32x4{});
#pragma unroll
          for (int e = 0; e < 4; ++e) {
            int rr = r * 16 + (lane >> 4) * 4 + e, cl = cc0 * 16 + (lane & 15);
            us val = f2b(a[e]);
            Ed[rr * 72 + cl] = val;
            Edt[cl * 72 + rr] = val;
          }
        }
      }
      __syncthreads();
      const us* Ent = (it & 1) ? Ebt : W1t;
#pragma unroll
      for (int s = 0; s < 2; ++s) {
        int j = w + s * 8;
        if (j < 10) {
          int r = TR_[j], cc0 = TC_[j];
          int l0 = cc0 & ~1, nk = (r - l0 + 2) >> 1;
          freg[s] = tile_range(W3, 72, Ent, 72, r, cc0, l0, nk, lane, f32x4{});
        }
      }
      __syncthreads();
    }
    // final accumulate of F_5
#pragma unroll
    for (int s = 0; s < 2; ++s) {
      int j = w + s * 8;
      if (j < 10) {
        int r = TR_[j], cc0 = TC_[j];
#pragma unroll
        for (int e = 0; e < 4; ++e) {
          int rr = r * 16 + (lane >> 4) * 4 + e, cl = cc0 * 16 + (lane & 15);
          W3[rr * 72 + cl] = f2b(b2f(W3[rr * 72 + cl]) + freg[s][e]);
        }
      }
    }
    __syncthreads();
    // ---------------- U = T.RHS (as Ut = RHS^T . T^T) ----------------
#pragma unroll
    for (int ct4 = 0; ct4 < 4; ++ct4) {
      f32x4 a = tile_range(Vt, 72, W3, 72, w, ct4, 0, 2, lane, f32x4{});
#pragma unroll
      for (int e = 0; e < 4; ++e)
        Ut[(w * 16 + (lane >> 4) * 4 + e) * 72 + ct4 * 16 + (lane & 15)] = f2b(a[e]);
    }
    __syncthreads();
    // ---------------- OS: O write + S update ----------------
    float lamC = __expf(bl_s[63]);
#pragma unroll
    for (int cc = 0; cc < 4; ++cc) {
      int ct4 = cbO + cc;
      f32x4 a = tile_range(WP, 72, Ut, 72, rtO, ct4, 0, 2, lane, f32x4{});
#pragma unroll
      for (int e = 0; e < 4; ++e) {
        int tt = rtO * 16 + (lane >> 4) * 4 + e;
        int vv = ct4 * 16 + (lane & 15);
        float val = __expf(bl_s[tt]) * o1[cc][e] + a[e];
        o[((bt0 + tt) * 32 + h) * 128 + vv] = f2b(val);
      }
    }
#pragma unroll
    for (int dt = 0; dt < 8; ++dt) {
      f32x4 a = tile_range(Ut, 72, Ktb, 72, w, dt, 0, 2, lane, f32x4{});
#pragma unroll
      for (int e = 0; e < 4; ++e) {
        int vv = w * 16 + (lane >> 4) * 4 + e, dd = dt * 16 + (lane & 15);
        Sb[vv * 136 + dd] = f2b(lamC * b2f(Sb[vv * 136 + dd]) + a[e]);
      }
    }
    __syncthreads();
  }
}

// ---------------- gated RMSNorm, in place (y over o) ----------------
__global__ __launch_bounds__(256) void rms_gate(us* oy,
    const us* __restrict__ z, const float* __restrict__ nw) {
  int wid = threadIdx.x >> 6, lane = threadIdx.x & 63;
  size_t base = ((size_t)blockIdx.x * 4 + wid) * 128;
  float o0 = b2f(oy[base + lane]), o1 = b2f(oy[base + lane + 64]);
  float ss = o0 * o0 + o1 * o1;
#pragma unroll
  for (int m = 1; m < 64; m <<= 1) ss += __shfl_xor(ss, m, 64);
  float r = rsqrtf(ss * (1.f / 128.f) + 1e-6f);
  float z0 = b2f(z[base + lane]), z1 = b2f(z[base + lane + 64]);
  z0 = z0 / (1.f + __expf(-z0));
  z1 = z1 / (1.f + __expf(-z1));
  oy[base + lane] = f2b(o0 * r * nw[lane] * z0);
  oy[base + lane + 64] = f2b(o1 * r * nw[lane + 64] * z1);
}

extern "C" void kernel_launch(void* const* d_in, const int* in_sizes, int n_in,
                              void* d_out, int out_size, void* d_ws, size_t ws_size,
                              hipStream_t stream) {
  const float* hs      = (const float*)d_in[0];
  const float* W_qkv   = (const float*)d_in[1];
  const float* W_z     = (const float*)d_in[2];
  const float* W_b     = (const float*)d_in[3];
  const float* W_a     = (const float*)d_in[4];
  const float* conv_w  = (const float*)d_in[5];
  const float* dt_bias = (const float*)d_in[6];
  const float* A_log   = (const float*)d_in[7];
  const float* norm_w  = (const float*)d_in[8];
  const float* W_out   = (const float*)d_in[9];
  float* out = (float*)d_out;

  char* ws = (char*)d_ws;
  const size_t MiB = 1u << 20;
  // layout (MiB), peak 172:
  //  0-8   wt (chunked weight^T staging)
  //  8-10  ba | 10-11 bl | 11-12 beta
  //  12-44 mixed chunk        \__ 12-76 o (bf16, after scan; y in-place)
  //  44-76 hs_bf (phase 1)    /
  //  76-108 q  -> hs_bf regen (phase 2, after scan)
  //  108-140 k \__ 108-172 z (after scan)
  //  140-204 v /
  us*    wt     = (us*)(ws);
  float* ba_buf = (float*)(ws + 8 * MiB);
  float* bl_g   = (float*)(ws + 10 * MiB);
  float* bt_g   = (float*)(ws + 11 * MiB);
  us*    mixed  = (us*)(ws + 12 * MiB);
  us*    o_buf  = (us*)(ws + 12 * MiB);
  us*    hs_bf0 = (us*)(ws + 44 * MiB);
  us*    q_buf  = (us*)(ws + 76 * MiB);
  us*    k_buf  = (us*)(ws + 108 * MiB);
  us*    v_buf  = (us*)(ws + 140 * MiB);
  us*    hs_bf1 = q_buf;
  us*    z_bf   = (us*)(ws + 108 * MiB);

  cvt_f32_bf16<<<2048, 256, 0, stream>>>(hs, hs_bf0, (long)8192 * 2048 / 4);

  // qkv projection in 4 chunks of 2048 cols, each followed by its conv
  for (int c = 0; c < 4; ++c) {
    transpose_cvt<<<dim3(64, 64), 256, 0, stream>>>(W_qkv, wt, 2048, 2048, 8192, c * 2048, 0);
    gemm_lds<true><<<dim3(64, 16), 256, 0, stream>>>(hs_bf0, wt, mixed, 2048, 2047, 2048, 2048, 0);
    const float* cwc = conv_w + (size_t)c * 2048 * 4;
    if (c == 0)      conv_chunk<0><<<8192, 256, 0, stream>>>(mixed, cwc, q_buf, 0);
    else if (c == 1) conv_chunk<1><<<8192, 256, 0, stream>>>(mixed, cwc, k_buf, 0);
    else if (c == 2) conv_chunk<2><<<8192, 256, 0, stream>>>(mixed, cwc, v_buf, 0);
    else             conv_chunk<2><<<8192, 256, 0, stream>>>(mixed, cwc, v_buf, 16);
  }
  // beta/a projections + gates
  transpose_cvt<<<dim3(1, 64), 256, 0, stream>>>(W_b, wt, 2048, 32, 32, 0, 0);
  transpose_cvt<<<dim3(1, 64), 256, 0, stream>>>(W_a, wt, 2048, 32, 32, 0, 32);
  gemm_lds<false><<<dim3(64, 1), 256, 0, stream>>>(hs_bf0, wt, ba_buf, 2048, 63, 64, 64, 0);
  gates_cumsum<<<1024, 256, 0, stream>>>(ba_buf, dt_bias, A_log, bl_g, bt_g);
  // chunked delta-rule scan -> o (overwrites mixed + hs_bf0)
  scan2<<<64, 512, 0, stream>>>(q_buf, k_buf, v_buf, bl_g, bt_g, o_buf);
  // regenerate hs_bf (into dead q region), then z projection (into dead k/v)
  cvt_f32_bf16<<<2048, 256, 0, stream>>>(hs, hs_bf1, (long)8192 * 2048 / 4);
  for (int c = 0; c < 2; ++c) {
    transpose_cvt<<<dim3(64, 64), 256, 0, stream>>>(W_z, wt, 2048, 2048, 4096, c * 2048, 0);
    gemm_lds<true><<<dim3(64, 16), 256, 0, stream>>>(hs_bf1, wt, z_bf, 2048, 2047, 2048, 4096, c * 2048);
  }
  // gated RMSNorm in place: o -> y
  rms_gate<<<65536, 256, 0, stream>>>(o_buf, z_bf, norm_w);
  // output projection in 2 chunks of 1024 cols
  for (int c = 0; c < 2; ++c) {
    transpose_cvt<<<dim3(32, 128), 256, 0, stream>>>(W_out, wt, 4096, 1024, 2048, c * 1024, 0);
    gemm_lds<false><<<dim3(64, 8), 256, 0, stream>>>(o_buf, wt, out, 4096, 1023, 1024, 2048, c * 1024);
  }
}

// Round 6
// 1761.065 us; speedup vs baseline: 18.3102x; 1.1836x over previous
//
#include <hip/hip_runtime.h>
#include <hip/hip_bf16.h>

// Qwen3.5 GatedDeltaNet: B=2, T=4096, D=2048, NV=32, NK=16, DK=DV=128, KC=4
// Round 6: two-pass scan. Pass 1 (chunk-parallel, 4096 blocks) computes
// T=(I+D)^-1 per chunk -> global. Pass 2 (sequential, 64 blocks) has only
// 4 barriers/chunk (was 15). GEMMs/convs unchanged from round 5.

typedef __attribute__((ext_vector_type(8))) short short8;
typedef __attribute__((ext_vector_type(4))) float f32x4;
typedef unsigned short us;

static __device__ __forceinline__ us f2b(float f) {
  __hip_bfloat16 h = __float2bfloat16(f);
  return __builtin_bit_cast(us, h);
}
static __device__ __forceinline__ float b2f(us u) {
  return __bfloat162float(__builtin_bit_cast(__hip_bfloat16, u));
}

// ---------------- fp32 -> bf16 elementwise ----------------
__global__ __launch_bounds__(256) void cvt_f32_bf16(const float* __restrict__ in,
    us* __restrict__ out, long n4) {
  long i = (long)blockIdx.x * 256 + threadIdx.x;
  long stride = (long)gridDim.x * 256;
  for (; i < n4; i += stride) {
    float4 f = reinterpret_cast<const float4*>(in)[i];
    ushort4 u;
    u.x = f2b(f.x); u.y = f2b(f.y); u.z = f2b(f.z); u.w = f2b(f.w);
    reinterpret_cast<ushort4*>(out)[i] = u;
  }
}

// ------- fp32 [K][Nfull] (col slice) -> bf16 [N][K] transpose-convert -------
__global__ __launch_bounds__(256) void transpose_cvt(const float* __restrict__ in,
    us* __restrict__ out, int K, int N, int Nfull, int coloff, int row_off) {
  __shared__ float tile[32][33];
  int tx = threadIdx.x & 31, ty = threadIdx.x >> 5;
  int n0 = blockIdx.x * 32, k0 = blockIdx.y * 32;
#pragma unroll
  for (int r = 0; r < 4; ++r) {
    int kk = k0 + ty + r * 8, nn = n0 + tx;
    tile[ty + r * 8][tx] = (kk < K && nn < N) ? in[(size_t)kk * Nfull + coloff + nn] : 0.f;
  }
  __syncthreads();
#pragma unroll
  for (int r = 0; r < 4; ++r) {
    int nn = n0 + ty + r * 8, kk = k0 + tx;
    if (nn < N && kk < K)
      out[(size_t)(nn + row_off) * K + kk] = f2b(tile[tx][ty + r * 8]);
  }
}

// ---------------- bf16 TN GEMM with global_load_lds staging ----------------
template <bool BF16OUT>
__global__ __launch_bounds__(256) void gemm_lds(const us* __restrict__ A,
    const us* __restrict__ B, void* __restrict__ Cout,
    int K, int Nb1, int Nvalid, int ldC, int coloff) {
  __shared__ us Ash[128 * 32];
  __shared__ us Bsh[128 * 32];
  int tid = threadIdx.x, w = tid >> 6, lane = tid & 63;
  int bm = blockIdx.x * 128, bn = blockIdx.y * 128;
  int wm = (w >> 1) * 64, wn = (w & 1) * 64;
  int r0 = w * 16 + (lane >> 2);
  int sx = ((lane & 3) ^ ((r0 >> 1) & 3)) * 8;
  const us* a0 = A + (size_t)(bm + r0) * K + sx;
  const us* a1 = a0 + (size_t)64 * K;
  int rb0 = bn + r0; if (rb0 > Nb1) rb0 = Nb1;
  int rb1 = bn + r0 + 64; if (rb1 > Nb1) rb1 = Nb1;
  const us* b0 = B + (size_t)rb0 * K + sx;
  const us* b1 = B + (size_t)rb1 * K + sx;
  us* lA0 = &Ash[w * 512]; us* lA1 = &Ash[2048 + w * 512];
  us* lB0 = &Bsh[w * 512]; us* lB1 = &Bsh[2048 + w * 512];
  f32x4 acc[4][4] = {};
  for (int kt = 0; kt < K; kt += 32) {
    __builtin_amdgcn_global_load_lds((const void*)(a0 + kt), (void*)lA0, 16, 0, 0);
    __builtin_amdgcn_global_load_lds((const void*)(a1 + kt), (void*)lA1, 16, 0, 0);
    __builtin_amdgcn_global_load_lds((const void*)(b0 + kt), (void*)lB0, 16, 0, 0);
    __builtin_amdgcn_global_load_lds((const void*)(b1 + kt), (void*)lB1, 16, 0, 0);
    __syncthreads();
    short8 af[4], bfr[4];
    int fr = lane & 15, j = lane >> 4;
#pragma unroll
    for (int f = 0; f < 4; ++f) {
      int Ra = wm + f * 16 + fr;
      af[f] = *reinterpret_cast<const short8*>(&Ash[Ra * 32 + ((j ^ ((Ra >> 1) & 3)) * 8)]);
      int Rb = wn + f * 16 + fr;
      bfr[f] = *reinterpret_cast<const short8*>(&Bsh[Rb * 32 + ((j ^ ((Rb >> 1) & 3)) * 8)]);
    }
#pragma unroll
    for (int i = 0; i < 4; ++i)
#pragma unroll
      for (int jj = 0; jj < 4; ++jj)
        acc[i][jj] = __builtin_amdgcn_mfma_f32_16x16x32_bf16(af[i], bfr[jj], acc[i][jj], 0, 0, 0);
    __syncthreads();
  }
#pragma unroll
  for (int i = 0; i < 4; ++i)
#pragma unroll
    for (int jj = 0; jj < 4; ++jj) {
      int c0 = bn + wn + jj * 16 + (lane & 15);
      if (c0 < Nvalid) {
#pragma unroll
        for (int e = 0; e < 4; ++e) {
          int r = bm + wm + i * 16 + (lane >> 4) * 4 + e;
          size_t off = (size_t)r * ldC + coloff + c0;
          if (BF16OUT) reinterpret_cast<us*>(Cout)[off] = f2b(acc[i][jj][e]);
          else reinterpret_cast<float*>(Cout)[off] = acc[i][jj][e];
        }
      }
    }
}

// -------- conv(KC=4)+silu (+l2norm) on a 2048-channel chunk --------
template <int MODE>
__global__ __launch_bounds__(256) void conv_chunk(const us* __restrict__ mixed,
    const float* __restrict__ cw, us* __restrict__ outp, int headbase) {
  int bt = blockIdx.x, b = bt >> 12, t = bt & 4095, tid = threadIdx.x;
  float x[8];
#pragma unroll
  for (int jj = 0; jj < 8; ++jj) {
    int c = jj * 256 + tid;
    float4 w4 = *reinterpret_cast<const float4*>(cw + (size_t)c * 4);
    float wv[4] = {w4.x, w4.y, w4.z, w4.w};
    float acc = 0.f;
#pragma unroll
    for (int i = 0; i < 4; ++i) {
      int tt = t - 3 + i;
      if (tt >= 0) acc += b2f(mixed[((size_t)(b * 4096 + tt)) * 2048 + c]) * wv[i];
    }
    x[jj] = acc / (1.f + __expf(-acc));
  }
  if (MODE < 2) {
    __shared__ float wsum[4][8];
    int wid = tid >> 6;
#pragma unroll
    for (int jj = 0; jj < 8; ++jj) {
      float s2 = x[jj] * x[jj];
#pragma unroll
      for (int m = 1; m < 64; m <<= 1) s2 += __shfl_xor(s2, m, 64);
      if ((tid & 63) == 0) wsum[wid][jj] = s2;
    }
    __syncthreads();
#pragma unroll
    for (int jj = 0; jj < 8; ++jj) {
      int w0 = (tid >> 7) * 2;
      float rn = rsqrtf(wsum[w0][jj] + wsum[w0 + 1][jj] + 1e-6f);
      int c = jj * 256 + tid;
      float val = x[jj] * rn * (MODE == 0 ? 0.08838834764831845f : 1.f);
      outp[((size_t)bt * 16 + (c >> 7)) * 128 + (c & 127)] = f2b(val);
    }
  } else {
#pragma unroll
    for (int jj = 0; jj < 8; ++jj) {
      int c = jj * 256 + tid;
      outp[((size_t)bt * 32 + headbase + (c >> 7)) * 128 + (c & 127)] = f2b(x[jj]);
    }
  }
}

// -------- gates: beta/g from ba, cumsum g within chunks of 64 --------
__global__ __launch_bounds__(256) void gates_cumsum(const float* __restrict__ ba,
    const float* __restrict__ dt_bias, const float* __restrict__ A_log,
    float* __restrict__ bl_g, float* __restrict__ beta_g) {
  int widx = blockIdx.x * 4 + (threadIdx.x >> 6);  // (b*32+h)*64 + chunk
  int lane = threadIdx.x & 63;
  int bh = widx >> 6, chunk = widx & 63;
  int b = bh >> 5, h = bh & 31;
  size_t btl = (size_t)b * 4096 + chunk * 64 + lane;
  float bv = ba[btl * 64 + h];
  float av = ba[btl * 64 + 32 + h];
  float beta = 1.f / (1.f + __expf(-bv));
  float xx = av + dt_bias[h];
  float sp = (xx > 20.f) ? xx : log1pf(__expf(xx));
  float g = -__expf(A_log[h]) * sp;
#pragma unroll
  for (int off = 1; off < 64; off <<= 1) {
    float n = __shfl_up(g, off, 64);
    if (lane >= off) g += n;
  }
  bl_g[(size_t)widx * 64 + lane] = g;
  beta_g[(size_t)widx * 64 + lane] = beta;
}

// ---------------- shared MFMA tile helper ----------------
static __device__ __forceinline__ f32x4 tile_range(const us* A, int lda,
    const us* B, int ldb, int rt, int ct, int l0, int nk, int lane, f32x4 acc) {
  const us* ar = A + (rt * 16 + (lane & 15)) * lda + l0 * 16 + (lane >> 4) * 8;
  const us* br = B + (ct * 16 + (lane & 15)) * ldb + l0 * 16 + (lane >> 4) * 8;
#pragma unroll
  for (int ks = 0; ks < nk; ++ks) {
    short8 a = *reinterpret_cast<const short8*>(ar + ks * 32);
    short8 bb = *reinterpret_cast<const short8*>(br + ks * 32);
    acc = __builtin_amdgcn_mfma_f32_16x16x32_bf16(a, bb, acc, 0, 0, 0);
  }
  return acc;
}

// =======================================================================
// Scan pass 1 (chunk-parallel): per (bh, chunk) compute T=(I+D)^-1 -> Tg.
// =======================================================================
__global__ __launch_bounds__(512, 1) void scan_p1(
    const us* __restrict__ k, const float* __restrict__ bl_g,
    const float* __restrict__ beta_g, us* __restrict__ Tg) {
  __shared__ us Kb[64 * 136];        // k [t][d]; aliased as Eb (ld 72) in chain
  __shared__ us Ebt[64 * 72];
  __shared__ us W1[64 * 72], W1t[64 * 72], W3[64 * 72];
  __shared__ float bl_s[64], bet_s[64];
  us* const Eb = Kb;

  int bid = blockIdx.x, bh = bid >> 6, c = bid & 63;
  int b = bh >> 5, h = bh & 31, hk = h >> 1;
  int tid = threadIdx.x, w = tid >> 6, lane = tid & 63;
  int row = tid >> 3, c16 = (tid & 7) * 16;
  size_t bt0 = (size_t)b * 4096 + c * 64;

  const int TR_[10] = {0, 1, 1, 2, 2, 2, 3, 3, 3, 3};
  const int TC_[10] = {0, 0, 1, 0, 1, 2, 0, 1, 2, 3};

  const us* kp = k + ((bt0 + row) * 16 + hk) * 128 + c16;
  uint4 kr0 = reinterpret_cast<const uint4*>(kp)[0];
  uint4 kr1 = reinterpret_cast<const uint4*>(kp)[1];
  int gbase = (bh * 64 + c) * 64;
  if (tid < 64) { bl_s[tid] = bl_g[gbase + tid]; bet_s[tid] = beta_g[gbase + tid]; }
  *reinterpret_cast<uint4*>(&Kb[row * 136 + c16]) = kr0;
  *reinterpret_cast<uint4*>(&Kb[row * 136 + c16 + 8]) = kr1;
  __syncthreads();
  // ---- D = masked scaled K K^T (full 64x64 write incl zeros) ----
  {
    int art = w & 3;
#pragma unroll
    for (int s = 0; s < 2; ++s) {
      int ct = (w >> 2) * 2 + s;
      f32x4 a = tile_range(Kb, 136, Kb, 136, art, ct, 0, 4, lane, f32x4{});
#pragma unroll
      for (int e = 0; e < 4; ++e) {
        int tr = art * 16 + (lane >> 4) * 4 + e;
        int cl = ct * 16 + (lane & 15);
        float dv = (cl < tr) ? bet_s[tr] * __expf(bl_s[tr] - bl_s[cl]) * a[e] : 0.f;
        W1[tr * 72 + cl] = f2b(dv);
        W1t[cl * 72 + tr] = f2b(dv);
        W3[tr * 72 + cl] = f2b((tr == cl ? 1.f : 0.f) - dv);
      }
    }
  }
  __syncthreads();
  // ---- T-chain: T=(I+D)^-1 = (I-D)(I+D^2)(I+D^4)(I+D^8)(I+D^16)(I+D^32) ----
  f32x4 freg[2] = {};
#pragma unroll
  for (int it = 1; it <= 5; ++it) {
    if (it > 1) {
#pragma unroll
      for (int s = 0; s < 2; ++s) {
        int j = w + s * 8;
        if (j < 10) {
          int r = TR_[j], cc0 = TC_[j];
#pragma unroll
          for (int e = 0; e < 4; ++e) {
            int rr = r * 16 + (lane >> 4) * 4 + e, cl = cc0 * 16 + (lane & 15);
            W3[rr * 72 + cl] = f2b(b2f(W3[rr * 72 + cl]) + freg[s][e]);
          }
        }
      }
    }
    if (it == 1) {  // zero stale complements of Eb (upper) / Ebt (lower)
      const int ZR[12] = {0, 0, 0, 1, 1, 2, 1, 2, 2, 3, 3, 3};
      const int ZC[12] = {1, 2, 3, 2, 3, 3, 0, 0, 1, 0, 1, 2};
#pragma unroll
      for (int u = 0; u < 12; ++u) {
        if ((u & 7) != w) continue;
        us* arr = (u < 6) ? Eb : Ebt;
        if (lane < 32) {
          int rr = ZR[u] * 16 + (lane >> 1);
          *reinterpret_cast<uint4*>(&arr[rr * 72 + ZC[u] * 16 + (lane & 1) * 8]) =
              make_uint4(0, 0, 0, 0);
        }
      }
    }
    const us* Es  = (it & 1) ? W1  : Eb;
    const us* Est = (it & 1) ? W1t : Ebt;
    us* Ed  = (it & 1) ? Eb  : W1;
    us* Edt = (it & 1) ? Ebt : W1t;
#pragma unroll
    for (int s = 0; s < 2; ++s) {
      int j = w + s * 8;
      if (j < 10) {
        int r = TR_[j], cc0 = TC_[j];
        int l0 = cc0 & ~1, nk = (r - l0 + 2) >> 1;
        f32x4 a = tile_range(Es, 72, Est, 72, r, cc0, l0, nk, lane, f32x4{});
#pragma unroll
        for (int e = 0; e < 4; ++e) {
          int rr = r * 16 + (lane >> 4) * 4 + e, cl = cc0 * 16 + (lane & 15);
          us val = f2b(a[e]);
          Ed[rr * 72 + cl] = val;
          Edt[cl * 72 + rr] = val;
        }
      }
    }
    __syncthreads();
    const us* Ent = (it & 1) ? Ebt : W1t;
#pragma unroll
    for (int s = 0; s < 2; ++s) {
      int j = w + s * 8;
      if (j < 10) {
        int r = TR_[j], cc0 = TC_[j];
        int l0 = cc0 & ~1, nk = (r - l0 + 2) >> 1;
        freg[s] = tile_range(W3, 72, Ent, 72, r, cc0, l0, nk, lane, f32x4{});
      }
    }
    __syncthreads();
  }
#pragma unroll
  for (int s = 0; s < 2; ++s) {
    int j = w + s * 8;
    if (j < 10) {
      int r = TR_[j], cc0 = TC_[j];
#pragma unroll
      for (int e = 0; e < 4; ++e) {
        int rr = r * 16 + (lane >> 4) * 4 + e, cl = cc0 * 16 + (lane & 15);
        W3[rr * 72 + cl] = f2b(b2f(W3[rr * 72 + cl]) + freg[s][e]);
      }
    }
  }
  __syncthreads();
  // ---- write T (64x64) to global ----
  *reinterpret_cast<uint4*>(&Tg[(size_t)bid * 4096 + tid * 8]) =
      *reinterpret_cast<const uint4*>(&W3[row * 72 + (tid & 7) * 8]);
}

// =======================================================================
// Scan pass 2 (sequential over chunks): 4 barriers/chunk.
// =======================================================================
__global__ __launch_bounds__(512, 1) void scan_p2(
    const us* __restrict__ q, const us* __restrict__ k, const us* __restrict__ v,
    const float* __restrict__ bl_g, const float* __restrict__ beta_g,
    const us* __restrict__ Tg, us* __restrict__ o) {
  __shared__ us Sb[128 * 136];   // S^T [v][d], persistent
  __shared__ us Kb[64 * 136];    // k raw [t][d]
  __shared__ us Qb[64 * 136];    // q raw [t][d]
  __shared__ us Ktb[128 * 72];   // e^{bC-b_t} K^T [d][t]
  __shared__ us Vt[128 * 72];    // beta*V^T -> RHS^T [v][t]
  __shared__ us Ut[128 * 72];    // U^T [v][t]
  __shared__ us W3[64 * 72];     // T (from pass 1)
  __shared__ us WP[64 * 72];     // P
  __shared__ float bl_s[64], bet_s[64];

  int bh = blockIdx.x, b = bh >> 5, h = bh & 31, hk = h >> 1;
  int tid = threadIdx.x, w = tid >> 6, lane = tid & 63;
  int row = tid >> 3, c16 = (tid & 7) * 16;

  for (int i = tid; i < (128 * 136) / 8; i += 512)
    reinterpret_cast<uint4*>(Sb)[i] = make_uint4(0, 0, 0, 0);
  __syncthreads();

  for (int c = 0; c < 64; ++c) {
    size_t bt0 = (size_t)b * 4096 + c * 64;
    // ---------------- LF ----------------
    const us* kp = k + ((bt0 + row) * 16 + hk) * 128 + c16;
    const us* qp = q + ((bt0 + row) * 16 + hk) * 128 + c16;
    const us* vp = v + ((bt0 + row) * 32 + h) * 128 + c16;
    uint4 kr0 = reinterpret_cast<const uint4*>(kp)[0];
    uint4 kr1 = reinterpret_cast<const uint4*>(kp)[1];
    uint4 qr0 = reinterpret_cast<const uint4*>(qp)[0];
    uint4 qr1 = reinterpret_cast<const uint4*>(qp)[1];
    uint4 vr0 = reinterpret_cast<const uint4*>(vp)[0];
    uint4 vr1 = reinterpret_cast<const uint4*>(vp)[1];
    int gbase = (bh * 64 + c) * 64;
    float blr = bl_g[gbase + row], blC = bl_g[gbase + 63];
    float bet = beta_g[gbase + row];
    if ((tid & 7) == 0) { bl_s[row] = blr; bet_s[row] = bet; }
    *reinterpret_cast<uint4*>(&Kb[row * 136 + c16]) = kr0;
    *reinterpret_cast<uint4*>(&Kb[row * 136 + c16 + 8]) = kr1;
    *reinterpret_cast<uint4*>(&Qb[row * 136 + c16]) = qr0;
    *reinterpret_cast<uint4*>(&Qb[row * 136 + c16 + 8]) = qr1;
    // T load: one uint4 per thread
    *reinterpret_cast<uint4*>(&W3[row * 72 + (tid & 7) * 8]) =
        *reinterpret_cast<const uint4*>(&Tg[((size_t)bh * 64 + c) * 4096 + tid * 8]);
    us kreg[16], vreg[16];
    *reinterpret_cast<uint4*>(kreg) = kr0; *reinterpret_cast<uint4*>(kreg + 8) = kr1;
    *reinterpret_cast<uint4*>(vreg) = vr0; *reinterpret_cast<uint4*>(vreg + 8) = vr1;
    float ksc = __expf(blC - blr);
#pragma unroll
    for (int i = 0; i < 16; ++i) Ktb[(c16 + i) * 72 + row] = f2b(ksc * b2f(kreg[i]));
#pragma unroll
    for (int i = 0; i < 16; ++i) Vt[(c16 + i) * 72 + row] = f2b(bet * b2f(vreg[i]));
    __syncthreads();
    // ---------------- G1: Q.S0 (regs) + P + RHS ----------------
    f32x4 o1[4];
    int rtO = w >> 1, cbO = (w & 1) * 4;
#pragma unroll
    for (int cc = 0; cc < 4; ++cc)
      o1[cc] = tile_range(Qb, 136, Sb, 136, rtO, cbO + cc, 0, 4, lane, f32x4{});
    {
      int art = w & 3;
#pragma unroll
      for (int s = 0; s < 2; ++s) {
        int ct = (w >> 2) * 2 + s;
        f32x4 a = tile_range(Qb, 136, Kb, 136, art, ct, 0, 4, lane, f32x4{});
#pragma unroll
        for (int e = 0; e < 4; ++e) {
          int tr = art * 16 + (lane >> 4) * 4 + e;
          int cl = ct * 16 + (lane & 15);
          float pv = (cl <= tr) ? __expf(bl_s[tr] - bl_s[cl]) * a[e] : 0.f;
          WP[tr * 72 + cl] = f2b(pv);
        }
      }
    }
#pragma unroll
    for (int ct4 = 0; ct4 < 4; ++ct4) {
      f32x4 a = tile_range(Sb, 136, Kb, 136, w, ct4, 0, 4, lane, f32x4{});
      int tt = ct4 * 16 + (lane & 15);
      float csc = bet_s[tt] * __expf(bl_s[tt]);
#pragma unroll
      for (int e = 0; e < 4; ++e) {
        int vv = w * 16 + (lane >> 4) * 4 + e;
        Vt[vv * 72 + tt] = f2b(b2f(Vt[vv * 72 + tt]) - csc * a[e]);
      }
    }
    __syncthreads();
    // ---------------- G2: Ut = RHS^T . T^T ----------------
#pragma unroll
    for (int ct4 = 0; ct4 < 4; ++ct4) {
      f32x4 a = tile_range(Vt, 72, W3, 72, w, ct4, 0, 2, lane, f32x4{});
#pragma unroll
      for (int e = 0; e < 4; ++e)
        Ut[(w * 16 + (lane >> 4) * 4 + e) * 72 + ct4 * 16 + (lane & 15)] = f2b(a[e]);
    }
    __syncthreads();
    // ---------------- OS: O write + S update ----------------
    float lamC = __expf(bl_s[63]);
#pragma unroll
    for (int cc = 0; cc < 4; ++cc) {
      int ct4 = cbO + cc;
      f32x4 a = tile_range(WP, 72, Ut, 72, rtO, ct4, 0, 2, lane, f32x4{});
#pragma unroll
      for (int e = 0; e < 4; ++e) {
        int tt = rtO * 16 + (lane >> 4) * 4 + e;
        int vv = ct4 * 16 + (lane & 15);
        float val = __expf(bl_s[tt]) * o1[cc][e] + a[e];
        o[((bt0 + tt) * 32 + h) * 128 + vv] = f2b(val);
      }
    }
#pragma unroll
    for (int dt = 0; dt < 8; ++dt) {
      f32x4 a = tile_range(Ut, 72, Ktb, 72, w, dt, 0, 2, lane, f32x4{});
#pragma unroll
      for (int e = 0; e < 4; ++e) {
        int vv = w * 16 + (lane >> 4) * 4 + e, dd = dt * 16 + (lane & 15);
        Sb[vv * 136 + dd] = f2b(lamC * b2f(Sb[vv * 136 + dd]) + a[e]);
      }
    }
    __syncthreads();
  }
}

// ---------------- gated RMSNorm, in place (y over o) ----------------
__global__ __launch_bounds__(256) void rms_gate(us* oy,
    const us* __restrict__ z, const float* __restrict__ nw) {
  int wid = threadIdx.x >> 6, lane = threadIdx.x & 63;
  size_t base = ((size_t)blockIdx.x * 4 + wid) * 128;
  float o0 = b2f(oy[base + lane]), o1 = b2f(oy[base + lane + 64]);
  float ss = o0 * o0 + o1 * o1;
#pragma unroll
  for (int m = 1; m < 64; m <<= 1) ss += __shfl_xor(ss, m, 64);
  float r = rsqrtf(ss * (1.f / 128.f) + 1e-6f);
  float z0 = b2f(z[base + lane]), z1 = b2f(z[base + lane + 64]);
  z0 = z0 / (1.f + __expf(-z0));
  z1 = z1 / (1.f + __expf(-z1));
  oy[base + lane] = f2b(o0 * r * nw[lane] * z0);
  oy[base + lane + 64] = f2b(o1 * r * nw[lane + 64] * z1);
}

extern "C" void kernel_launch(void* const* d_in, const int* in_sizes, int n_in,
                              void* d_out, int out_size, void* d_ws, size_t ws_size,
                              hipStream_t stream) {
  const float* hs      = (const float*)d_in[0];
  const float* W_qkv   = (const float*)d_in[1];
  const float* W_z     = (const float*)d_in[2];
  const float* W_b     = (const float*)d_in[3];
  const float* W_a     = (const float*)d_in[4];
  const float* conv_w  = (const float*)d_in[5];
  const float* dt_bias = (const float*)d_in[6];
  const float* A_log   = (const float*)d_in[7];
  const float* norm_w  = (const float*)d_in[8];
  const float* W_out   = (const float*)d_in[9];
  float* out = (float*)d_out;

  char* ws = (char*)d_ws;
  const size_t MiB = 1u << 20;
  // layout (MiB), peak 228:
  //  0-2  ba | 2-3 bl | 3-4 bt
  //  4-12 wt (steps 2-3; reused step 6)   \__ 4-36 Tg (scan, after ba GEMM)
  //  12-36 (Tg tail)                      /
  //  36-68  mixed  \__ 36-100 o (pass 2 output; y in place)
  //  68-100 hs_bf0 /
  //  100-132 q  -> hs_bf1 (z phase)
  //  132-164 k
  //  164-228 v -> z (after pass 2)
  float* ba_buf = (float*)(ws);
  float* bl_g   = (float*)(ws + 2 * MiB);
  float* bt_g   = (float*)(ws + 3 * MiB);
  us*    wt     = (us*)(ws + 4 * MiB);
  us*    Tg     = (us*)(ws + 4 * MiB);
  us*    mixed  = (us*)(ws + 36 * MiB);
  us*    o_buf  = (us*)(ws + 36 * MiB);
  us*    hs_bf0 = (us*)(ws + 68 * MiB);
  us*    q_buf  = (us*)(ws + 100 * MiB);
  us*    hs_bf1 = q_buf;
  us*    k_buf  = (us*)(ws + 132 * MiB);
  us*    v_buf  = (us*)(ws + 164 * MiB);
  us*    z_bf   = v_buf;

  cvt_f32_bf16<<<2048, 256, 0, stream>>>(hs, hs_bf0, (long)8192 * 2048 / 4);

  // qkv projection in 4 chunks of 2048 cols, each followed by its conv
  for (int c = 0; c < 4; ++c) {
    transpose_cvt<<<dim3(64, 64), 256, 0, stream>>>(W_qkv, wt, 2048, 2048, 8192, c * 2048, 0);
    gemm_lds<true><<<dim3(64, 16), 256, 0, stream>>>(hs_bf0, wt, mixed, 2048, 2047, 2048, 2048, 0);
    const float* cwc = conv_w + (size_t)c * 2048 * 4;
    if (c == 0)      conv_chunk<0><<<8192, 256, 0, stream>>>(mixed, cwc, q_buf, 0);
    else if (c == 1) conv_chunk<1><<<8192, 256, 0, stream>>>(mixed, cwc, k_buf, 0);
    else if (c == 2) conv_chunk<2><<<8192, 256, 0, stream>>>(mixed, cwc, v_buf, 0);
    else             conv_chunk<2><<<8192, 256, 0, stream>>>(mixed, cwc, v_buf, 16);
  }
  // beta/a projections + gates
  transpose_cvt<<<dim3(1, 64), 256, 0, stream>>>(W_b, wt, 2048, 32, 32, 0, 0);
  transpose_cvt<<<dim3(1, 64), 256, 0, stream>>>(W_a, wt, 2048, 32, 32, 0, 32);
  gemm_lds<false><<<dim3(64, 1), 256, 0, stream>>>(hs_bf0, wt, ba_buf, 2048, 63, 64, 64, 0);
  gates_cumsum<<<1024, 256, 0, stream>>>(ba_buf, dt_bias, A_log, bl_g, bt_g);
  // two-pass chunked delta-rule scan
  scan_p1<<<4096, 512, 0, stream>>>(k_buf, bl_g, bt_g, Tg);
  scan_p2<<<64, 512, 0, stream>>>(q_buf, k_buf, v_buf, bl_g, bt_g, Tg, o_buf);
  // regenerate hs_bf (into dead q region), then z projection (into dead v)
  cvt_f32_bf16<<<2048, 256, 0, stream>>>(hs, hs_bf1, (long)8192 * 2048 / 4);
  for (int c = 0; c < 2; ++c) {
    transpose_cvt<<<dim3(64, 64), 256, 0, stream>>>(W_z, wt, 2048, 2048, 4096, c * 2048, 0);
    gemm_lds<true><<<dim3(64, 16), 256, 0, stream>>>(hs_bf1, wt, z_bf, 2048, 2047, 2048, 4096, c * 2048);
  }
  // gated RMSNorm in place: o -> y
  rms_gate<<<65536, 256, 0, stream>>>(o_buf, z_bf, norm_w);
  // output projection in 2 chunks of 1024 cols
  for (int c = 0; c < 2; ++c) {
    transpose_cvt<<<dim3(32, 128), 256, 0, stream>>>(W_out, wt, 4096, 1024, 2048, c * 1024, 0);
    gemm_lds<false><<<dim3(64, 8), 256, 0, stream>>>(o_buf, wt, out, 4096, 1023, 1024, 2048, c * 1024);
  }
}

// Round 7
// 1468.085 us; speedup vs baseline: 21.9642x; 1.1996x over previous
//
#include <hip/hip_runtime.h>
#include <hip/hip_bf16.h>

// Qwen3.5 GatedDeltaNet: B=2, T=4096, D=2048, NV=32, NK=16, DK=DV=128, KC=4
// Round 7: v-split scan_p2 (4 slices -> 256 blocks, same-XCD per bh) with
// register prefetch of next chunk; gemm BK=64 (half the barriers) + XCD swizzle.

typedef __attribute__((ext_vector_type(8))) short short8;
typedef __attribute__((ext_vector_type(4))) float f32x4;
typedef unsigned short us;

static __device__ __forceinline__ us f2b(float f) {
  __hip_bfloat16 h = __float2bfloat16(f);
  return __builtin_bit_cast(us, h);
}
static __device__ __forceinline__ float b2f(us u) {
  return __bfloat162float(__builtin_bit_cast(__hip_bfloat16, u));
}

// ---------------- fp32 -> bf16 elementwise ----------------
__global__ __launch_bounds__(256) void cvt_f32_bf16(const float* __restrict__ in,
    us* __restrict__ out, long n4) {
  long i = (long)blockIdx.x * 256 + threadIdx.x;
  long stride = (long)gridDim.x * 256;
  for (; i < n4; i += stride) {
    float4 f = reinterpret_cast<const float4*>(in)[i];
    ushort4 u;
    u.x = f2b(f.x); u.y = f2b(f.y); u.z = f2b(f.z); u.w = f2b(f.w);
    reinterpret_cast<ushort4*>(out)[i] = u;
  }
}

// ------- fp32 [K][Nfull] (col slice) -> bf16 [N][K] transpose-convert -------
__global__ __launch_bounds__(256) void transpose_cvt(const float* __restrict__ in,
    us* __restrict__ out, int K, int N, int Nfull, int coloff, int row_off) {
  __shared__ float tile[32][33];
  int tx = threadIdx.x & 31, ty = threadIdx.x >> 5;
  int n0 = blockIdx.x * 32, k0 = blockIdx.y * 32;
#pragma unroll
  for (int r = 0; r < 4; ++r) {
    int kk = k0 + ty + r * 8, nn = n0 + tx;
    tile[ty + r * 8][tx] = (kk < K && nn < N) ? in[(size_t)kk * Nfull + coloff + nn] : 0.f;
  }
  __syncthreads();
#pragma unroll
  for (int r = 0; r < 4; ++r) {
    int nn = n0 + ty + r * 8, kk = k0 + tx;
    if (nn < N && kk < K)
      out[(size_t)(nn + row_off) * K + kk] = f2b(tile[tx][ty + r * 8]);
  }
}

// ---------------- bf16 TN GEMM, BK=64, global_load_lds, XCD swizzle ----------
// A[M][K] * B[Nrows][K]^T -> C[M][*], 128x128 tile, 4 waves.
// LDS [128 rows][64 k] linear; 16B-slot swizzle: lds_slot s holds global slot
// s ^ (row&7)  (source pre-swizzled; read XORs the same).
template <bool BF16OUT>
__global__ __launch_bounds__(256) void gemm_lds(const us* __restrict__ A,
    const us* __restrict__ B, void* __restrict__ Cout,
    int K, int Nb1, int Nvalid, int ldC, int coloff) {
  __shared__ us Ash[128 * 64];
  __shared__ us Bsh[128 * 64];
  int tid = threadIdx.x, w = tid >> 6, lane = tid & 63;
  // bijective XCD swizzle (nwg % 8 == 0 for all launches here)
  int lin = blockIdx.y * gridDim.x + blockIdx.x;
  int nwg = gridDim.x * gridDim.y;
  int wg = (lin & 7) * (nwg >> 3) + (lin >> 3);
  int bx = wg % gridDim.x, by = wg / gridDim.x;
  int bm = bx * 128, bn = by * 128;
  int wm = (w >> 1) * 64, wn = (w & 1) * 64;
  const us* aP[4]; const us* bP[4]; us* lA[4]; us* lB[4];
#pragma unroll
  for (int i = 0; i < 4; ++i) {
    int idx = i * 256 + tid;
    int row = idx >> 3;
    int sg = ((idx & 7) ^ (row & 7)) * 8;
    aP[i] = A + (size_t)(bm + row) * K + sg;
    int rb = bn + row; if (rb > Nb1) rb = Nb1;
    bP[i] = B + (size_t)rb * K + sg;
    lA[i] = &Ash[(i * 256 + w * 64) * 8];
    lB[i] = &Bsh[(i * 256 + w * 64) * 8];
  }
  f32x4 acc[4][4] = {};
  int fr = lane & 15, j = lane >> 4;
  for (int kt = 0; kt < K; kt += 64) {
#pragma unroll
    for (int i = 0; i < 4; ++i)
      __builtin_amdgcn_global_load_lds((const void*)(aP[i] + kt), (void*)lA[i], 16, 0, 0);
#pragma unroll
    for (int i = 0; i < 4; ++i)
      __builtin_amdgcn_global_load_lds((const void*)(bP[i] + kt), (void*)lB[i], 16, 0, 0);
    __syncthreads();
#pragma unroll
    for (int ks = 0; ks < 2; ++ks) {
      short8 af[4], bfr[4];
#pragma unroll
      for (int f = 0; f < 4; ++f) {
        int Ra = wm + f * 16 + fr;
        af[f] = *reinterpret_cast<const short8*>(&Ash[Ra * 64 + (((ks * 4 + j) ^ (Ra & 7)) * 8)]);
        int Rb = wn + f * 16 + fr;
        bfr[f] = *reinterpret_cast<const short8*>(&Bsh[Rb * 64 + (((ks * 4 + j) ^ (Rb & 7)) * 8)]);
      }
#pragma unroll
      for (int i = 0; i < 4; ++i)
#pragma unroll
        for (int jj = 0; jj < 4; ++jj)
          acc[i][jj] = __builtin_amdgcn_mfma_f32_16x16x32_bf16(af[i], bfr[jj], acc[i][jj], 0, 0, 0);
    }
    __syncthreads();
  }
#pragma unroll
  for (int i = 0; i < 4; ++i)
#pragma unroll
    for (int jj = 0; jj < 4; ++jj) {
      int c0 = bn + wn + jj * 16 + (lane & 15);
      if (c0 < Nvalid) {
#pragma unroll
        for (int e = 0; e < 4; ++e) {
          int r = bm + wm + i * 16 + (lane >> 4) * 4 + e;
          size_t off = (size_t)r * ldC + coloff + c0;
          if (BF16OUT) reinterpret_cast<us*>(Cout)[off] = f2b(acc[i][jj][e]);
          else reinterpret_cast<float*>(Cout)[off] = acc[i][jj][e];
        }
      }
    }
}

// -------- conv(KC=4)+silu (+l2norm) on a 2048-channel chunk --------
template <int MODE>
__global__ __launch_bounds__(256) void conv_chunk(const us* __restrict__ mixed,
    const float* __restrict__ cw, us* __restrict__ outp, int headbase) {
  int bt = blockIdx.x, b = bt >> 12, t = bt & 4095, tid = threadIdx.x;
  float x[8];
#pragma unroll
  for (int jj = 0; jj < 8; ++jj) {
    int c = jj * 256 + tid;
    float4 w4 = *reinterpret_cast<const float4*>(cw + (size_t)c * 4);
    float wv[4] = {w4.x, w4.y, w4.z, w4.w};
    float acc = 0.f;
#pragma unroll
    for (int i = 0; i < 4; ++i) {
      int tt = t - 3 + i;
      if (tt >= 0) acc += b2f(mixed[((size_t)(b * 4096 + tt)) * 2048 + c]) * wv[i];
    }
    x[jj] = acc / (1.f + __expf(-acc));
  }
  if (MODE < 2) {
    __shared__ float wsum[4][8];
    int wid = tid >> 6;
#pragma unroll
    for (int jj = 0; jj < 8; ++jj) {
      float s2 = x[jj] * x[jj];
#pragma unroll
      for (int m = 1; m < 64; m <<= 1) s2 += __shfl_xor(s2, m, 64);
      if ((tid & 63) == 0) wsum[wid][jj] = s2;
    }
    __syncthreads();
#pragma unroll
    for (int jj = 0; jj < 8; ++jj) {
      int w0 = (tid >> 7) * 2;
      float rn = rsqrtf(wsum[w0][jj] + wsum[w0 + 1][jj] + 1e-6f);
      int c = jj * 256 + tid;
      float val = x[jj] * rn * (MODE == 0 ? 0.08838834764831845f : 1.f);
      outp[((size_t)bt * 16 + (c >> 7)) * 128 + (c & 127)] = f2b(val);
    }
  } else {
#pragma unroll
    for (int jj = 0; jj < 8; ++jj) {
      int c = jj * 256 + tid;
      outp[((size_t)bt * 32 + headbase + (c >> 7)) * 128 + (c & 127)] = f2b(x[jj]);
    }
  }
}

// -------- gates: beta/g from ba, cumsum g within chunks of 64 --------
__global__ __launch_bounds__(256) void gates_cumsum(const float* __restrict__ ba,
    const float* __restrict__ dt_bias, const float* __restrict__ A_log,
    float* __restrict__ bl_g, float* __restrict__ beta_g) {
  int widx = blockIdx.x * 4 + (threadIdx.x >> 6);  // (b*32+h)*64 + chunk
  int lane = threadIdx.x & 63;
  int bh = widx >> 6, chunk = widx & 63;
  int b = bh >> 5, h = bh & 31;
  size_t btl = (size_t)b * 4096 + chunk * 64 + lane;
  float bv = ba[btl * 64 + h];
  float av = ba[btl * 64 + 32 + h];
  float beta = 1.f / (1.f + __expf(-bv));
  float xx = av + dt_bias[h];
  float sp = (xx > 20.f) ? xx : log1pf(__expf(xx));
  float g = -__expf(A_log[h]) * sp;
#pragma unroll
  for (int off = 1; off < 64; off <<= 1) {
    float n = __shfl_up(g, off, 64);
    if (lane >= off) g += n;
  }
  bl_g[(size_t)widx * 64 + lane] = g;
  beta_g[(size_t)widx * 64 + lane] = beta;
}

// ---------------- shared MFMA tile helper ----------------
static __device__ __forceinline__ f32x4 tile_range(const us* A, int lda,
    const us* B, int ldb, int rt, int ct, int l0, int nk, int lane, f32x4 acc) {
  const us* ar = A + (rt * 16 + (lane & 15)) * lda + l0 * 16 + (lane >> 4) * 8;
  const us* br = B + (ct * 16 + (lane & 15)) * ldb + l0 * 16 + (lane >> 4) * 8;
#pragma unroll
  for (int ks = 0; ks < nk; ++ks) {
    short8 a = *reinterpret_cast<const short8*>(ar + ks * 32);
    short8 bb = *reinterpret_cast<const short8*>(br + ks * 32);
    acc = __builtin_amdgcn_mfma_f32_16x16x32_bf16(a, bb, acc, 0, 0, 0);
  }
  return acc;
}

// =======================================================================
// Scan pass 1 (chunk-parallel): per (bh, chunk) compute T=(I+D)^-1 -> Tg.
// =======================================================================
__global__ __launch_bounds__(512, 1) void scan_p1(
    const us* __restrict__ k, const float* __restrict__ bl_g,
    const float* __restrict__ beta_g, us* __restrict__ Tg) {
  __shared__ us Kb[64 * 136];        // k [t][d]; aliased as Eb (ld 72) in chain
  __shared__ us Ebt[64 * 72];
  __shared__ us W1[64 * 72], W1t[64 * 72], W3[64 * 72];
  __shared__ float bl_s[64], bet_s[64];
  us* const Eb = Kb;

  int bid = blockIdx.x, bh = bid >> 6, c = bid & 63;
  int b = bh >> 5, h = bh & 31, hk = h >> 1;
  int tid = threadIdx.x, w = tid >> 6, lane = tid & 63;
  int row = tid >> 3, c16 = (tid & 7) * 16;
  size_t bt0 = (size_t)b * 4096 + c * 64;

  const int TR_[10] = {0, 1, 1, 2, 2, 2, 3, 3, 3, 3};
  const int TC_[10] = {0, 0, 1, 0, 1, 2, 0, 1, 2, 3};

  const us* kp = k + ((bt0 + row) * 16 + hk) * 128 + c16;
  uint4 kr0 = reinterpret_cast<const uint4*>(kp)[0];
  uint4 kr1 = reinterpret_cast<const uint4*>(kp)[1];
  int gbase = (bh * 64 + c) * 64;
  if (tid < 64) { bl_s[tid] = bl_g[gbase + tid]; bet_s[tid] = beta_g[gbase + tid]; }
  *reinterpret_cast<uint4*>(&Kb[row * 136 + c16]) = kr0;
  *reinterpret_cast<uint4*>(&Kb[row * 136 + c16 + 8]) = kr1;
  __syncthreads();
  {
    int art = w & 3;
#pragma unroll
    for (int s = 0; s < 2; ++s) {
      int ct = (w >> 2) * 2 + s;
      f32x4 a = tile_range(Kb, 136, Kb, 136, art, ct, 0, 4, lane, f32x4{});
#pragma unroll
      for (int e = 0; e < 4; ++e) {
        int tr = art * 16 + (lane >> 4) * 4 + e;
        int cl = ct * 16 + (lane & 15);
        float dv = (cl < tr) ? bet_s[tr] * __expf(bl_s[tr] - bl_s[cl]) * a[e] : 0.f;
        W1[tr * 72 + cl] = f2b(dv);
        W1t[cl * 72 + tr] = f2b(dv);
        W3[tr * 72 + cl] = f2b((tr == cl ? 1.f : 0.f) - dv);
      }
    }
  }
  __syncthreads();
  f32x4 freg[2] = {};
#pragma unroll
  for (int it = 1; it <= 5; ++it) {
    if (it > 1) {
#pragma unroll
      for (int s = 0; s < 2; ++s) {
        int j = w + s * 8;
        if (j < 10) {
          int r = TR_[j], cc0 = TC_[j];
#pragma unroll
          for (int e = 0; e < 4; ++e) {
            int rr = r * 16 + (lane >> 4) * 4 + e, cl = cc0 * 16 + (lane & 15);
            W3[rr * 72 + cl] = f2b(b2f(W3[rr * 72 + cl]) + freg[s][e]);
          }
        }
      }
    }
    if (it == 1) {
      const int ZR[12] = {0, 0, 0, 1, 1, 2, 1, 2, 2, 3, 3, 3};
      const int ZC[12] = {1, 2, 3, 2, 3, 3, 0, 0, 1, 0, 1, 2};
#pragma unroll
      for (int u = 0; u < 12; ++u) {
        if ((u & 7) != w) continue;
        us* arr = (u < 6) ? Eb : Ebt;
        if (lane < 32) {
          int rr = ZR[u] * 16 + (lane >> 1);
          *reinterpret_cast<uint4*>(&arr[rr * 72 + ZC[u] * 16 + (lane & 1) * 8]) =
              make_uint4(0, 0, 0, 0);
        }
      }
    }
    const us* Es  = (it & 1) ? W1  : Eb;
    const us* Est = (it & 1) ? W1t : Ebt;
    us* Ed  = (it & 1) ? Eb  : W1;
    us* Edt = (it & 1) ? Ebt : W1t;
#pragma unroll
    for (int s = 0; s < 2; ++s) {
      int j = w + s * 8;
      if (j < 10) {
        int r = TR_[j], cc0 = TC_[j];
        int l0 = cc0 & ~1, nk = (r - l0 + 2) >> 1;
        f32x4 a = tile_range(Es, 72, Est, 72, r, cc0, l0, nk, lane, f32x4{});
#pragma unroll
        for (int e = 0; e < 4; ++e) {
          int rr = r * 16 + (lane >> 4) * 4 + e, cl = cc0 * 16 + (lane & 15);
          us val = f2b(a[e]);
          Ed[rr * 72 + cl] = val;
          Edt[cl * 72 + rr] = val;
        }
      }
    }
    __syncthreads();
    const us* Ent = (it & 1) ? Ebt : W1t;
#pragma unroll
    for (int s = 0; s < 2; ++s) {
      int j = w + s * 8;
      if (j < 10) {
        int r = TR_[j], cc0 = TC_[j];
        int l0 = cc0 & ~1, nk = (r - l0 + 2) >> 1;
        freg[s] = tile_range(W3, 72, Ent, 72, r, cc0, l0, nk, lane, f32x4{});
      }
    }
    __syncthreads();
  }
#pragma unroll
  for (int s = 0; s < 2; ++s) {
    int j = w + s * 8;
    if (j < 10) {
      int r = TR_[j], cc0 = TC_[j];
#pragma unroll
      for (int e = 0; e < 4; ++e) {
        int rr = r * 16 + (lane >> 4) * 4 + e, cl = cc0 * 16 + (lane & 15);
        W3[rr * 72 + cl] = f2b(b2f(W3[rr * 72 + cl]) + freg[s][e]);
      }
    }
  }
  __syncthreads();
  *reinterpret_cast<uint4*>(&Tg[(size_t)bid * 4096 + tid * 8]) =
      *reinterpret_cast<const uint4*>(&W3[row * 72 + (tid & 7) * 8]);
}

// =======================================================================
// Scan pass 2: sequential over chunks, split 4x over V (256 blocks).
// bid = vs*64 + bh  (same bh -> same XCD for q/k/T L2 sharing).
// Register-prefetch of chunk c+1 hides HBM latency under compute.
// =======================================================================
__global__ __launch_bounds__(512, 1) void scan_p2(
    const us* __restrict__ q, const us* __restrict__ k, const us* __restrict__ v,
    const float* __restrict__ bl_g, const float* __restrict__ beta_g,
    const us* __restrict__ Tg, us* __restrict__ o) {
  __shared__ us Sb[32 * 136];    // S^T slice [v 32][d 128], persistent
  __shared__ us Kb[64 * 136];    // k raw [t][d]
  __shared__ us Qb[64 * 136];    // q raw [t][d]
  __shared__ us Ktb[128 * 72];   // e^{bC-b_t} K^T [d][t]
  __shared__ us Vt[32 * 72];     // beta*V^T slice -> RHS^T [v][t]
  __shared__ us Ut[32 * 72];     // U^T slice [v][t]
  __shared__ us W3[64 * 72];     // T (from pass 1)
  __shared__ us WP[64 * 72];     // P
  __shared__ float bl_s[64], bet_s[64];

  int bid = blockIdx.x, vs = bid >> 6, bh = bid & 63;
  int b = bh >> 5, h = bh & 31, hk = h >> 1;
  int tid = threadIdx.x, w = tid >> 6, lane = tid & 63;
  int row = tid >> 3, c16 = (tid & 7) * 16;

  for (int i = tid; i < (32 * 136) / 8; i += 512)
    reinterpret_cast<uint4*>(Sb)[i] = make_uint4(0, 0, 0, 0);
  __syncthreads();

  // ---- prefetch chunk 0 into regs ----
  uint4 kr0, kr1, qr0, qr1, vr, Tr;
  float blr, blC, bet, betv;
  int vrow = (tid & 255) >> 2, vseg = tid & 3;
  auto load_regs = [&](int c) {
    size_t bt0 = (size_t)b * 4096 + c * 64;
    const us* kp = k + ((bt0 + row) * 16 + hk) * 128 + c16;
    const us* qp = q + ((bt0 + row) * 16 + hk) * 128 + c16;
    kr0 = reinterpret_cast<const uint4*>(kp)[0];
    kr1 = reinterpret_cast<const uint4*>(kp)[1];
    qr0 = reinterpret_cast<const uint4*>(qp)[0];
    qr1 = reinterpret_cast<const uint4*>(qp)[1];
    Tr = *reinterpret_cast<const uint4*>(&Tg[((size_t)bh * 64 + c) * 4096 + tid * 8]);
    int gbase = (bh * 64 + c) * 64;
    blr = bl_g[gbase + row];
    blC = bl_g[gbase + 63];
    bet = beta_g[gbase + row];
    if (tid < 256) {
      vr = *reinterpret_cast<const uint4*>(
          v + ((bt0 + vrow) * 32 + h) * 128 + vs * 32 + vseg * 8);
      betv = beta_g[gbase + vrow];
    }
  };
  load_regs(0);

  for (int c = 0; c < 64; ++c) {
    size_t bt0 = (size_t)b * 4096 + c * 64;
    // ---------------- LF: write regs -> LDS, then prefetch c+1 ----------------
    if ((tid & 7) == 0) { bl_s[row] = blr; bet_s[row] = bet; }
    *reinterpret_cast<uint4*>(&Kb[row * 136 + c16]) = kr0;
    *reinterpret_cast<uint4*>(&Kb[row * 136 + c16 + 8]) = kr1;
    *reinterpret_cast<uint4*>(&Qb[row * 136 + c16]) = qr0;
    *reinterpret_cast<uint4*>(&Qb[row * 136 + c16 + 8]) = qr1;
    *reinterpret_cast<uint4*>(&W3[row * 72 + (tid & 7) * 8]) = Tr;
    {
      us kreg[16];
      *reinterpret_cast<uint4*>(kreg) = kr0; *reinterpret_cast<uint4*>(kreg + 8) = kr1;
      float ksc = __expf(blC - blr);
#pragma unroll
      for (int i = 0; i < 16; ++i) Ktb[(c16 + i) * 72 + row] = f2b(ksc * b2f(kreg[i]));
    }
    if (tid < 256) {
      us vreg[8];
      *reinterpret_cast<uint4*>(vreg) = vr;
#pragma unroll
      for (int i = 0; i < 8; ++i) Vt[(vseg * 8 + i) * 72 + vrow] = f2b(betv * b2f(vreg[i]));
    }
    load_regs(c < 63 ? c + 1 : 63);
    __syncthreads();
    // ---------------- G1: Q.S0 (regs) + P + RHS ----------------
    int rtO = w >> 1, ctv = w & 1;
    f32x4 o1 = tile_range(Qb, 136, Sb, 136, rtO, ctv, 0, 4, lane, f32x4{});
    {
      int art = w & 3;
#pragma unroll
      for (int s = 0; s < 2; ++s) {
        int ct = (w >> 2) * 2 + s;
        f32x4 a = tile_range(Qb, 136, Kb, 136, art, ct, 0, 4, lane, f32x4{});
#pragma unroll
        for (int e = 0; e < 4; ++e) {
          int tr = art * 16 + (lane >> 4) * 4 + e;
          int cl = ct * 16 + (lane & 15);
          float pv = (cl <= tr) ? __expf(bl_s[tr] - bl_s[cl]) * a[e] : 0.f;
          WP[tr * 72 + cl] = f2b(pv);
        }
      }
    }
    {
      int vrt = w >> 2, ct = w & 3;
      f32x4 a = tile_range(Sb, 136, Kb, 136, vrt, ct, 0, 4, lane, f32x4{});
      int tt = ct * 16 + (lane & 15);
      float csc = bet_s[tt] * __expf(bl_s[tt]);
#pragma unroll
      for (int e = 0; e < 4; ++e) {
        int vv = vrt * 16 + (lane >> 4) * 4 + e;
        Vt[vv * 72 + tt] = f2b(b2f(Vt[vv * 72 + tt]) - csc * a[e]);
      }
    }
    __syncthreads();
    // ---------------- G2: Ut = RHS^T . T^T ----------------
    {
      int vrt = w >> 2, ct = w & 3;
      f32x4 a = tile_range(Vt, 72, W3, 72, vrt, ct, 0, 2, lane, f32x4{});
#pragma unroll
      for (int e = 0; e < 4; ++e)
        Ut[(vrt * 16 + (lane >> 4) * 4 + e) * 72 + ct * 16 + (lane & 15)] = f2b(a[e]);
    }
    __syncthreads();
    // ---------------- OS: O write + S update ----------------
    float lamC = __expf(bl_s[63]);
    {
      f32x4 a = tile_range(WP, 72, Ut, 72, rtO, ctv, 0, 2, lane, f32x4{});
#pragma unroll
      for (int e = 0; e < 4; ++e) {
        int tt = rtO * 16 + (lane >> 4) * 4 + e;
        int vv = vs * 32 + ctv * 16 + (lane & 15);
        float val = __expf(bl_s[tt]) * o1[e] + a[e];
        o[((bt0 + tt) * 32 + h) * 128 + vv] = f2b(val);
      }
    }
#pragma unroll
    for (int s = 0; s < 2; ++s) {
      int ti = w * 2 + s;
      int vrt = ti >> 3, dt = ti & 7;
      f32x4 a = tile_range(Ut, 72, Ktb, 72, vrt, dt, 0, 2, lane, f32x4{});
#pragma unroll
      for (int e = 0; e < 4; ++e) {
        int vv = vrt * 16 + (lane >> 4) * 4 + e, dd = dt * 16 + (lane & 15);
        Sb[vv * 136 + dd] = f2b(lamC * b2f(Sb[vv * 136 + dd]) + a[e]);
      }
    }
    __syncthreads();
  }
}

// ---------------- gated RMSNorm, in place (y over o) ----------------
__global__ __launch_bounds__(256) void rms_gate(us* oy,
    const us* __restrict__ z, const float* __restrict__ nw) {
  int wid = threadIdx.x >> 6, lane = threadIdx.x & 63;
  size_t base = ((size_t)blockIdx.x * 4 + wid) * 128;
  float o0 = b2f(oy[base + lane]), o1 = b2f(oy[base + lane + 64]);
  float ss = o0 * o0 + o1 * o1;
#pragma unroll
  for (int m = 1; m < 64; m <<= 1) ss += __shfl_xor(ss, m, 64);
  float r = rsqrtf(ss * (1.f / 128.f) + 1e-6f);
  float z0 = b2f(z[base + lane]), z1 = b2f(z[base + lane + 64]);
  z0 = z0 / (1.f + __expf(-z0));
  z1 = z1 / (1.f + __expf(-z1));
  oy[base + lane] = f2b(o0 * r * nw[lane] * z0);
  oy[base + lane + 64] = f2b(o1 * r * nw[lane + 64] * z1);
}

extern "C" void kernel_launch(void* const* d_in, const int* in_sizes, int n_in,
                              void* d_out, int out_size, void* d_ws, size_t ws_size,
                              hipStream_t stream) {
  const float* hs      = (const float*)d_in[0];
  const float* W_qkv   = (const float*)d_in[1];
  const float* W_z     = (const float*)d_in[2];
  const float* W_b     = (const float*)d_in[3];
  const float* W_a     = (const float*)d_in[4];
  const float* conv_w  = (const float*)d_in[5];
  const float* dt_bias = (const float*)d_in[6];
  const float* A_log   = (const float*)d_in[7];
  const float* norm_w  = (const float*)d_in[8];
  const float* W_out   = (const float*)d_in[9];
  float* out = (float*)d_out;

  char* ws = (char*)d_ws;
  const size_t MiB = 1u << 20;
  // layout (MiB), peak 228 (proven safe):
  //  0-2 ba | 2-3 bl | 3-4 bt | 4-12 wt (\ 4-36 Tg after ba GEMM)
  //  36-68 mixed \__ 36-100 o | 68-100 hs_bf0 | 100-132 q -> hs_bf1
  //  132-164 k | 164-228 v -> z
  float* ba_buf = (float*)(ws);
  float* bl_g   = (float*)(ws + 2 * MiB);
  float* bt_g   = (float*)(ws + 3 * MiB);
  us*    wt     = (us*)(ws + 4 * MiB);
  us*    Tg     = (us*)(ws + 4 * MiB);
  us*    mixed  = (us*)(ws + 36 * MiB);
  us*    o_buf  = (us*)(ws + 36 * MiB);
  us*    hs_bf0 = (us*)(ws + 68 * MiB);
  us*    q_buf  = (us*)(ws + 100 * MiB);
  us*    hs_bf1 = q_buf;
  us*    k_buf  = (us*)(ws + 132 * MiB);
  us*    v_buf  = (us*)(ws + 164 * MiB);
  us*    z_bf   = v_buf;

  cvt_f32_bf16<<<2048, 256, 0, stream>>>(hs, hs_bf0, (long)8192 * 2048 / 4);

  for (int c = 0; c < 4; ++c) {
    transpose_cvt<<<dim3(64, 64), 256, 0, stream>>>(W_qkv, wt, 2048, 2048, 8192, c * 2048, 0);
    gemm_lds<true><<<dim3(64, 16), 256, 0, stream>>>(hs_bf0, wt, mixed, 2048, 2047, 2048, 2048, 0);
    const float* cwc = conv_w + (size_t)c * 2048 * 4;
    if (c == 0)      conv_chunk<0><<<8192, 256, 0, stream>>>(mixed, cwc, q_buf, 0);
    else if (c == 1) conv_chunk<1><<<8192, 256, 0, stream>>>(mixed, cwc, k_buf, 0);
    else if (c == 2) conv_chunk<2><<<8192, 256, 0, stream>>>(mixed, cwc, v_buf, 0);
    else             conv_chunk<2><<<8192, 256, 0, stream>>>(mixed, cwc, v_buf, 16);
  }
  transpose_cvt<<<dim3(1, 64), 256, 0, stream>>>(W_b, wt, 2048, 32, 32, 0, 0);
  transpose_cvt<<<dim3(1, 64), 256, 0, stream>>>(W_a, wt, 2048, 32, 32, 0, 32);
  gemm_lds<false><<<dim3(64, 1), 256, 0, stream>>>(hs_bf0, wt, ba_buf, 2048, 63, 64, 64, 0);
  gates_cumsum<<<1024, 256, 0, stream>>>(ba_buf, dt_bias, A_log, bl_g, bt_g);
  scan_p1<<<4096, 512, 0, stream>>>(k_buf, bl_g, bt_g, Tg);
  scan_p2<<<256, 512, 0, stream>>>(q_buf, k_buf, v_buf, bl_g, bt_g, Tg, o_buf);
  cvt_f32_bf16<<<2048, 256, 0, stream>>>(hs, hs_bf1, (long)8192 * 2048 / 4);
  for (int c = 0; c < 2; ++c) {
    transpose_cvt<<<dim3(64, 64), 256, 0, stream>>>(W_z, wt, 2048, 2048, 4096, c * 2048, 0);
    gemm_lds<true><<<dim3(64, 16), 256, 0, stream>>>(hs_bf1, wt, z_bf, 2048, 2047, 2048, 4096, c * 2048);
  }
  rms_gate<<<65536, 256, 0, stream>>>(o_buf, z_bf, norm_w);
  for (int c = 0; c < 2; ++c) {
    transpose_cvt<<<dim3(32, 128), 256, 0, stream>>>(W_out, wt, 4096, 1024, 2048, c * 1024, 0);
    gemm_lds<false><<<dim3(64, 8), 256, 0, stream>>>(o_buf, wt, out, 4096, 1023, 1024, 2048, c * 1024);
  }
}

// Round 8
// 1225.247 us; speedup vs baseline: 26.3175x; 1.1982x over previous
//
#include <hip/hip_runtime.h>
#include <hip/hip_bf16.h>

// Qwen3.5 GatedDeltaNet: B=2, T=4096, D=2048, NV=32, NK=16, DK=DV=128, KC=4
// Round 8: 256^2 8-wave double-buffered GEMM (4-phase staged pipeline,
// swizzled LDS, XCD swizzle) replaces 128^2 for all big projections.
// Scan (two-pass, v-split) unchanged from round 7.

typedef __attribute__((ext_vector_type(8))) short short8;
typedef __attribute__((ext_vector_type(4))) float f32x4;
typedef unsigned short us;

static __device__ __forceinline__ us f2b(float f) {
  __hip_bfloat16 h = __float2bfloat16(f);
  return __builtin_bit_cast(us, h);
}
static __device__ __forceinline__ float b2f(us u) {
  return __bfloat162float(__builtin_bit_cast(__hip_bfloat16, u));
}

// ---------------- fp32 -> bf16 elementwise ----------------
__global__ __launch_bounds__(256) void cvt_f32_bf16(const float* __restrict__ in,
    us* __restrict__ out, long n4) {
  long i = (long)blockIdx.x * 256 + threadIdx.x;
  long stride = (long)gridDim.x * 256;
  for (; i < n4; i += stride) {
    float4 f = reinterpret_cast<const float4*>(in)[i];
    ushort4 u;
    u.x = f2b(f.x); u.y = f2b(f.y); u.z = f2b(f.z); u.w = f2b(f.w);
    reinterpret_cast<ushort4*>(out)[i] = u;
  }
}

// ------- fp32 [K][Nfull] (col slice) -> bf16 [N][K] transpose-convert -------
__global__ __launch_bounds__(256) void transpose_cvt(const float* __restrict__ in,
    us* __restrict__ out, int K, int N, int Nfull, int coloff, int row_off) {
  __shared__ float tile[32][33];
  int tx = threadIdx.x & 31, ty = threadIdx.x >> 5;
  int n0 = blockIdx.x * 32, k0 = blockIdx.y * 32;
#pragma unroll
  for (int r = 0; r < 4; ++r) {
    int kk = k0 + ty + r * 8, nn = n0 + tx;
    tile[ty + r * 8][tx] = (kk < K && nn < N) ? in[(size_t)kk * Nfull + coloff + nn] : 0.f;
  }
  __syncthreads();
#pragma unroll
  for (int r = 0; r < 4; ++r) {
    int nn = n0 + ty + r * 8, kk = k0 + tx;
    if (nn < N && kk < K)
      out[(size_t)(nn + row_off) * K + kk] = f2b(tile[tx][ty + r * 8]);
  }
}

// ================= 256x256 8-wave double-buffered TN GEMM =================
// A[M][K] * B[N][K]^T -> C[M][*]. BK=64. 512 threads, waves 2(M)x4(N).
// LDS: 2 buffers x (A[256][64] + B[256][64]) bf16 = 128 KiB.
// Slot swizzle (16B units): lds slot s of row r holds global slot s^(r&7);
// source pre-swizzled, reads XOR the same (validated in round-7 kernel).
// Per K-tile: 4 phases { stage 2 gload_lds (next tile quarter) ; 12 ds_read ;
// 16 MFMA } + one __syncthreads (implicit vmcnt(0) drain).
template <bool BF16OUT>
__global__ __launch_bounds__(512, 1) void gemm256(const us* __restrict__ A,
    const us* __restrict__ B, void* __restrict__ Cout, int K, int ldC) {
  __shared__ us Abuf[2][256 * 64];
  __shared__ us Bbuf[2][256 * 64];
  int tid = threadIdx.x, w = tid >> 6, lane = tid & 63;
  int wr = w >> 2, wc = w & 3;
  int fr = lane & 15, j4 = lane >> 4;
  // bijective XCD swizzle (nwg % 8 == 0 for all launches here)
  int lin = blockIdx.y * gridDim.x + blockIdx.x;
  int nwg = gridDim.x * gridDim.y;
  int wg = (lin & 7) * (nwg >> 3) + (lin >> 3);
  int bx = wg % gridDim.x, by = wg / gridDim.x;
  size_t bm = (size_t)bx * 256, bn = (size_t)by * 256;

  // staging: unit u covers rows [u*64, u*64+64) of the 256-row tile.
  const us *aG[4], *bG[4];
  us *aL[2][4], *bL[2][4];
#pragma unroll
  for (int u = 0; u < 4; ++u) {
    int idx = u * 512 + tid;
    int row = idx >> 3, sl = idx & 7;
    int sg = (sl ^ (row & 7)) * 8;
    aG[u] = A + (bm + row) * K + sg;
    bG[u] = B + (bn + row) * K + sg;
    int lbase = (u * 64 + w * 8) * 64;  // wave-uniform; HW adds lane*16B
#pragma unroll
    for (int bf = 0; bf < 2; ++bf) {
      aL[bf][u] = &Abuf[bf][lbase];
      bL[bf][u] = &Bbuf[bf][lbase];
    }
  }

  f32x4 acc[8][4] = {};
  // prologue: stage tile 0 into buffer 0
#pragma unroll
  for (int u = 0; u < 4; ++u) {
    __builtin_amdgcn_global_load_lds((const void*)aG[u], (void*)aL[0][u], 16, 0, 0);
    __builtin_amdgcn_global_load_lds((const void*)bG[u], (void*)bL[0][u], 16, 0, 0);
  }
  __syncthreads();

  int nt = K >> 6;
  for (int t = 0; t < nt; ++t) {
    int cur = t & 1, nxt = cur ^ 1;
    const us* Ac = Abuf[cur];
    const us* Bc = Bbuf[cur];
    int kt1 = (t + 1) << 6;
    bool more = (t + 1 < nt);
#pragma unroll
    for (int q = 0; q < 4; ++q) {
      if (more) {
        __builtin_amdgcn_global_load_lds((const void*)(aG[q] + kt1), (void*)aL[nxt][q], 16, 0, 0);
        __builtin_amdgcn_global_load_lds((const void*)(bG[q] + kt1), (void*)bL[nxt][q], 16, 0, 0);
      }
      short8 a0[2], a1[2], bfv[4][2];
      int Ra0 = wr * 128 + 2 * q * 16 + fr;
      int Ra1 = Ra0 + 16;
#pragma unroll
      for (int ks = 0; ks < 2; ++ks) {
        a0[ks] = *reinterpret_cast<const short8*>(&Ac[Ra0 * 64 + (((ks * 4 + j4) ^ (Ra0 & 7)) * 8)]);
        a1[ks] = *reinterpret_cast<const short8*>(&Ac[Ra1 * 64 + (((ks * 4 + j4) ^ (Ra1 & 7)) * 8)]);
#pragma unroll
        for (int fj = 0; fj < 4; ++fj) {
          int Rb = wc * 64 + fj * 16 + fr;
          bfv[fj][ks] = *reinterpret_cast<const short8*>(&Bc[Rb * 64 + (((ks * 4 + j4) ^ (Rb & 7)) * 8)]);
        }
      }
      __builtin_amdgcn_s_setprio(1);
#pragma unroll
      for (int ks = 0; ks < 2; ++ks)
#pragma unroll
        for (int fj = 0; fj < 4; ++fj) {
          acc[2 * q][fj] = __builtin_amdgcn_mfma_f32_16x16x32_bf16(a0[ks], bfv[fj][ks], acc[2 * q][fj], 0, 0, 0);
          acc[2 * q + 1][fj] = __builtin_amdgcn_mfma_f32_16x16x32_bf16(a1[ks], bfv[fj][ks], acc[2 * q + 1][fj], 0, 0, 0);
        }
      __builtin_amdgcn_s_setprio(0);
    }
    __syncthreads();  // drains vmcnt(0): next tile fully landed in buf[nxt]
  }
  // epilogue
#pragma unroll
  for (int fi = 0; fi < 8; ++fi)
#pragma unroll
    for (int fj = 0; fj < 4; ++fj) {
      size_t col = bn + wc * 64 + fj * 16 + fr;
#pragma unroll
      for (int e = 0; e < 4; ++e) {
        size_t r = bm + wr * 128 + fi * 16 + j4 * 4 + e;
        size_t off = r * ldC + col;
        if (BF16OUT) reinterpret_cast<us*>(Cout)[off] = f2b(acc[fi][fj][e]);
        else reinterpret_cast<float*>(Cout)[off] = acc[fi][fj][e];
      }
    }
}

// ---------------- 128^2 GEMM (kept for the tiny ba projection) ----------------
__global__ __launch_bounds__(256) void gemm_lds_f32(const us* __restrict__ A,
    const us* __restrict__ B, float* __restrict__ Cout,
    int K, int Nb1, int Nvalid, int ldC) {
  __shared__ us Ash[128 * 64];
  __shared__ us Bsh[128 * 64];
  int tid = threadIdx.x, w = tid >> 6, lane = tid & 63;
  int bm = blockIdx.x * 128, bn = blockIdx.y * 128;
  int wm = (w >> 1) * 64, wn = (w & 1) * 64;
  const us* aP[4]; const us* bP[4]; us* lA[4]; us* lB[4];
#pragma unroll
  for (int i = 0; i < 4; ++i) {
    int idx = i * 256 + tid;
    int row = idx >> 3;
    int sg = ((idx & 7) ^ (row & 7)) * 8;
    aP[i] = A + (size_t)(bm + row) * K + sg;
    int rb = bn + row; if (rb > Nb1) rb = Nb1;
    bP[i] = B + (size_t)rb * K + sg;
    lA[i] = &Ash[(i * 256 + w * 64) * 8];
    lB[i] = &Bsh[(i * 256 + w * 64) * 8];
  }
  f32x4 acc[4][4] = {};
  int fr = lane & 15, j = lane >> 4;
  for (int kt = 0; kt < K; kt += 64) {
#pragma unroll
    for (int i = 0; i < 4; ++i)
      __builtin_amdgcn_global_load_lds((const void*)(aP[i] + kt), (void*)lA[i], 16, 0, 0);
#pragma unroll
    for (int i = 0; i < 4; ++i)
      __builtin_amdgcn_global_load_lds((const void*)(bP[i] + kt), (void*)lB[i], 16, 0, 0);
    __syncthreads();
#pragma unroll
    for (int ks = 0; ks < 2; ++ks) {
      short8 af[4], bfr[4];
#pragma unroll
      for (int f = 0; f < 4; ++f) {
        int Ra = wm + f * 16 + fr;
        af[f] = *reinterpret_cast<const short8*>(&Ash[Ra * 64 + (((ks * 4 + j) ^ (Ra & 7)) * 8)]);
        int Rb = wn + f * 16 + fr;
        bfr[f] = *reinterpret_cast<const short8*>(&Bsh[Rb * 64 + (((ks * 4 + j) ^ (Rb & 7)) * 8)]);
      }
#pragma unroll
      for (int i = 0; i < 4; ++i)
#pragma unroll
        for (int jj = 0; jj < 4; ++jj)
          acc[i][jj] = __builtin_amdgcn_mfma_f32_16x16x32_bf16(af[i], bfr[jj], acc[i][jj], 0, 0, 0);
    }
    __syncthreads();
  }
#pragma unroll
  for (int i = 0; i < 4; ++i)
#pragma unroll
    for (int jj = 0; jj < 4; ++jj) {
      int c0 = bn + wn + jj * 16 + (lane & 15);
      if (c0 < Nvalid) {
#pragma unroll
        for (int e = 0; e < 4; ++e) {
          int r = bm + wm + i * 16 + (lane >> 4) * 4 + e;
          Cout[(size_t)r * ldC + c0] = acc[i][jj][e];
        }
      }
    }
}

// -------- conv(KC=4)+silu (+l2norm) on a 2048-channel chunk --------
template <int MODE>
__global__ __launch_bounds__(256) void conv_chunk(const us* __restrict__ mixed,
    const float* __restrict__ cw, us* __restrict__ outp, int headbase) {
  int bt = blockIdx.x, b = bt >> 12, t = bt & 4095, tid = threadIdx.x;
  float x[8];
#pragma unroll
  for (int jj = 0; jj < 8; ++jj) {
    int c = jj * 256 + tid;
    float4 w4 = *reinterpret_cast<const float4*>(cw + (size_t)c * 4);
    float wv[4] = {w4.x, w4.y, w4.z, w4.w};
    float acc = 0.f;
#pragma unroll
    for (int i = 0; i < 4; ++i) {
      int tt = t - 3 + i;
      if (tt >= 0) acc += b2f(mixed[((size_t)(b * 4096 + tt)) * 2048 + c]) * wv[i];
    }
    x[jj] = acc / (1.f + __expf(-acc));
  }
  if (MODE < 2) {
    __shared__ float wsum[4][8];
    int wid = tid >> 6;
#pragma unroll
    for (int jj = 0; jj < 8; ++jj) {
      float s2 = x[jj] * x[jj];
#pragma unroll
      for (int m = 1; m < 64; m <<= 1) s2 += __shfl_xor(s2, m, 64);
      if ((tid & 63) == 0) wsum[wid][jj] = s2;
    }
    __syncthreads();
#pragma unroll
    for (int jj = 0; jj < 8; ++jj) {
      int w0 = (tid >> 7) * 2;
      float rn = rsqrtf(wsum[w0][jj] + wsum[w0 + 1][jj] + 1e-6f);
      int c = jj * 256 + tid;
      float val = x[jj] * rn * (MODE == 0 ? 0.08838834764831845f : 1.f);
      outp[((size_t)bt * 16 + (c >> 7)) * 128 + (c & 127)] = f2b(val);
    }
  } else {
#pragma unroll
    for (int jj = 0; jj < 8; ++jj) {
      int c = jj * 256 + tid;
      outp[((size_t)bt * 32 + headbase + (c >> 7)) * 128 + (c & 127)] = f2b(x[jj]);
    }
  }
}

// -------- gates: beta/g from ba, cumsum g within chunks of 64 --------
__global__ __launch_bounds__(256) void gates_cumsum(const float* __restrict__ ba,
    const float* __restrict__ dt_bias, const float* __restrict__ A_log,
    float* __restrict__ bl_g, float* __restrict__ beta_g) {
  int widx = blockIdx.x * 4 + (threadIdx.x >> 6);  // (b*32+h)*64 + chunk
  int lane = threadIdx.x & 63;
  int bh = widx >> 6, chunk = widx & 63;
  int b = bh >> 5, h = bh & 31;
  size_t btl = (size_t)b * 4096 + chunk * 64 + lane;
  float bv = ba[btl * 64 + h];
  float av = ba[btl * 64 + 32 + h];
  float beta = 1.f / (1.f + __expf(-bv));
  float xx = av + dt_bias[h];
  float sp = (xx > 20.f) ? xx : log1pf(__expf(xx));
  float g = -__expf(A_log[h]) * sp;
#pragma unroll
  for (int off = 1; off < 64; off <<= 1) {
    float n = __shfl_up(g, off, 64);
    if (lane >= off) g += n;
  }
  bl_g[(size_t)widx * 64 + lane] = g;
  beta_g[(size_t)widx * 64 + lane] = beta;
}

// ---------------- shared MFMA tile helper ----------------
static __device__ __forceinline__ f32x4 tile_range(const us* A, int lda,
    const us* B, int ldb, int rt, int ct, int l0, int nk, int lane, f32x4 acc) {
  const us* ar = A + (rt * 16 + (lane & 15)) * lda + l0 * 16 + (lane >> 4) * 8;
  const us* br = B + (ct * 16 + (lane & 15)) * ldb + l0 * 16 + (lane >> 4) * 8;
#pragma unroll
  for (int ks = 0; ks < nk; ++ks) {
    short8 a = *reinterpret_cast<const short8*>(ar + ks * 32);
    short8 bb = *reinterpret_cast<const short8*>(br + ks * 32);
    acc = __builtin_amdgcn_mfma_f32_16x16x32_bf16(a, bb, acc, 0, 0, 0);
  }
  return acc;
}

// =======================================================================
// Scan pass 1 (chunk-parallel): per (bh, chunk) compute T=(I+D)^-1 -> Tg.
// =======================================================================
__global__ __launch_bounds__(512, 1) void scan_p1(
    const us* __restrict__ k, const float* __restrict__ bl_g,
    const float* __restrict__ beta_g, us* __restrict__ Tg) {
  __shared__ us Kb[64 * 136];        // k [t][d]; aliased as Eb (ld 72) in chain
  __shared__ us Ebt[64 * 72];
  __shared__ us W1[64 * 72], W1t[64 * 72], W3[64 * 72];
  __shared__ float bl_s[64], bet_s[64];
  us* const Eb = Kb;

  int bid = blockIdx.x, bh = bid >> 6, c = bid & 63;
  int b = bh >> 5, h = bh & 31, hk = h >> 1;
  int tid = threadIdx.x, w = tid >> 6, lane = tid & 63;
  int row = tid >> 3, c16 = (tid & 7) * 16;
  size_t bt0 = (size_t)b * 4096 + c * 64;

  const int TR_[10] = {0, 1, 1, 2, 2, 2, 3, 3, 3, 3};
  const int TC_[10] = {0, 0, 1, 0, 1, 2, 0, 1, 2, 3};

  const us* kp = k + ((bt0 + row) * 16 + hk) * 128 + c16;
  uint4 kr0 = reinterpret_cast<const uint4*>(kp)[0];
  uint4 kr1 = reinterpret_cast<const uint4*>(kp)[1];
  int gbase = (bh * 64 + c) * 64;
  if (tid < 64) { bl_s[tid] = bl_g[gbase + tid]; bet_s[tid] = beta_g[gbase + tid]; }
  *reinterpret_cast<uint4*>(&Kb[row * 136 + c16]) = kr0;
  *reinterpret_cast<uint4*>(&Kb[row * 136 + c16 + 8]) = kr1;
  __syncthreads();
  {
    int art = w & 3;
#pragma unroll
    for (int s = 0; s < 2; ++s) {
      int ct = (w >> 2) * 2 + s;
      f32x4 a = tile_range(Kb, 136, Kb, 136, art, ct, 0, 4, lane, f32x4{});
#pragma unroll
      for (int e = 0; e < 4; ++e) {
        int tr = art * 16 + (lane >> 4) * 4 + e;
        int cl = ct * 16 + (lane & 15);
        float dv = (cl < tr) ? bet_s[tr] * __expf(bl_s[tr] - bl_s[cl]) * a[e] : 0.f;
        W1[tr * 72 + cl] = f2b(dv);
        W1t[cl * 72 + tr] = f2b(dv);
        W3[tr * 72 + cl] = f2b((tr == cl ? 1.f : 0.f) - dv);
      }
    }
  }
  __syncthreads();
  f32x4 freg[2] = {};
#pragma unroll
  for (int it = 1; it <= 5; ++it) {
    if (it > 1) {
#pragma unroll
      for (int s = 0; s < 2; ++s) {
        int j = w + s * 8;
        if (j < 10) {
          int r = TR_[j], cc0 = TC_[j];
#pragma unroll
          for (int e = 0; e < 4; ++e) {
            int rr = r * 16 + (lane >> 4) * 4 + e, cl = cc0 * 16 + (lane & 15);
            W3[rr * 72 + cl] = f2b(b2f(W3[rr * 72 + cl]) + freg[s][e]);
          }
        }
      }
    }
    if (it == 1) {
      const int ZR[12] = {0, 0, 0, 1, 1, 2, 1, 2, 2, 3, 3, 3};
      const int ZC[12] = {1, 2, 3, 2, 3, 3, 0, 0, 1, 0, 1, 2};
#pragma unroll
      for (int u = 0; u < 12; ++u) {
        if ((u & 7) != w) continue;
        us* arr = (u < 6) ? Eb : Ebt;
        if (lane < 32) {
          int rr = ZR[u] * 16 + (lane >> 1);
          *reinterpret_cast<uint4*>(&arr[rr * 72 + ZC[u] * 16 + (lane & 1) * 8]) =
              make_uint4(0, 0, 0, 0);
        }
      }
    }
    const us* Es  = (it & 1) ? W1  : Eb;
    const us* Est = (it & 1) ? W1t : Ebt;
    us* Ed  = (it & 1) ? Eb  : W1;
    us* Edt = (it & 1) ? Ebt : W1t;
#pragma unroll
    for (int s = 0; s < 2; ++s) {
      int j = w + s * 8;
      if (j < 10) {
        int r = TR_[j], cc0 = TC_[j];
        int l0 = cc0 & ~1, nk = (r - l0 + 2) >> 1;
        f32x4 a = tile_range(Es, 72, Est, 72, r, cc0, l0, nk, lane, f32x4{});
#pragma unroll
        for (int e = 0; e < 4; ++e) {
          int rr = r * 16 + (lane >> 4) * 4 + e, cl = cc0 * 16 + (lane & 15);
          us val = f2b(a[e]);
          Ed[rr * 72 + cl] = val;
          Edt[cl * 72 + rr] = val;
        }
      }
    }
    __syncthreads();
    const us* Ent = (it & 1) ? Ebt : W1t;
#pragma unroll
    for (int s = 0; s < 2; ++s) {
      int j = w + s * 8;
      if (j < 10) {
        int r = TR_[j], cc0 = TC_[j];
        int l0 = cc0 & ~1, nk = (r - l0 + 2) >> 1;
        freg[s] = tile_range(W3, 72, Ent, 72, r, cc0, l0, nk, lane, f32x4{});
      }
    }
    __syncthreads();
  }
#pragma unroll
  for (int s = 0; s < 2; ++s) {
    int j = w + s * 8;
    if (j < 10) {
      int r = TR_[j], cc0 = TC_[j];
#pragma unroll
      for (int e = 0; e < 4; ++e) {
        int rr = r * 16 + (lane >> 4) * 4 + e, cl = cc0 * 16 + (lane & 15);
        W3[rr * 72 + cl] = f2b(b2f(W3[rr * 72 + cl]) + freg[s][e]);
      }
    }
  }
  __syncthreads();
  *reinterpret_cast<uint4*>(&Tg[(size_t)bid * 4096 + tid * 8]) =
      *reinterpret_cast<const uint4*>(&W3[row * 72 + (tid & 7) * 8]);
}

// =======================================================================
// Scan pass 2: sequential over chunks, split 4x over V (256 blocks).
// =======================================================================
__global__ __launch_bounds__(512, 1) void scan_p2(
    const us* __restrict__ q, const us* __restrict__ k, const us* __restrict__ v,
    const float* __restrict__ bl_g, const float* __restrict__ beta_g,
    const us* __restrict__ Tg, us* __restrict__ o) {
  __shared__ us Sb[32 * 136];    // S^T slice [v 32][d 128], persistent
  __shared__ us Kb[64 * 136];    // k raw [t][d]
  __shared__ us Qb[64 * 136];    // q raw [t][d]
  __shared__ us Ktb[128 * 72];   // e^{bC-b_t} K^T [d][t]
  __shared__ us Vt[32 * 72];     // beta*V^T slice -> RHS^T [v][t]
  __shared__ us Ut[32 * 72];     // U^T slice [v][t]
  __shared__ us W3[64 * 72];     // T (from pass 1)
  __shared__ us WP[64 * 72];     // P
  __shared__ float bl_s[64], bet_s[64];

  int bid = blockIdx.x, vs = bid >> 6, bh = bid & 63;
  int b = bh >> 5, h = bh & 31, hk = h >> 1;
  int tid = threadIdx.x, w = tid >> 6, lane = tid & 63;
  int row = tid >> 3, c16 = (tid & 7) * 16;

  for (int i = tid; i < (32 * 136) / 8; i += 512)
    reinterpret_cast<uint4*>(Sb)[i] = make_uint4(0, 0, 0, 0);
  __syncthreads();

  uint4 kr0, kr1, qr0, qr1, vr, Tr;
  float blr, blC, bet, betv;
  int vrow = (tid & 255) >> 2, vseg = tid & 3;
  auto load_regs = [&](int c) {
    size_t bt0 = (size_t)b * 4096 + c * 64;
    const us* kp = k + ((bt0 + row) * 16 + hk) * 128 + c16;
    const us* qp = q + ((bt0 + row) * 16 + hk) * 128 + c16;
    kr0 = reinterpret_cast<const uint4*>(kp)[0];
    kr1 = reinterpret_cast<const uint4*>(kp)[1];
    qr0 = reinterpret_cast<const uint4*>(qp)[0];
    qr1 = reinterpret_cast<const uint4*>(qp)[1];
    Tr = *reinterpret_cast<const uint4*>(&Tg[((size_t)bh * 64 + c) * 4096 + tid * 8]);
    int gbase = (bh * 64 + c) * 64;
    blr = bl_g[gbase + row];
    blC = bl_g[gbase + 63];
    bet = beta_g[gbase + row];
    if (tid < 256) {
      vr = *reinterpret_cast<const uint4*>(
          v + ((bt0 + vrow) * 32 + h) * 128 + vs * 32 + vseg * 8);
      betv = beta_g[gbase + vrow];
    }
  };
  load_regs(0);

  for (int c = 0; c < 64; ++c) {
    size_t bt0 = (size_t)b * 4096 + c * 64;
    if ((tid & 7) == 0) { bl_s[row] = blr; bet_s[row] = bet; }
    *reinterpret_cast<uint4*>(&Kb[row * 136 + c16]) = kr0;
    *reinterpret_cast<uint4*>(&Kb[row * 136 + c16 + 8]) = kr1;
    *reinterpret_cast<uint4*>(&Qb[row * 136 + c16]) = qr0;
    *reinterpret_cast<uint4*>(&Qb[row * 136 + c16 + 8]) = qr1;
    *reinterpret_cast<uint4*>(&W3[row * 72 + (tid & 7) * 8]) = Tr;
    {
      us kreg[16];
      *reinterpret_cast<uint4*>(kreg) = kr0; *reinterpret_cast<uint4*>(kreg + 8) = kr1;
      float ksc = __expf(blC - blr);
#pragma unroll
      for (int i = 0; i < 16; ++i) Ktb[(c16 + i) * 72 + row] = f2b(ksc * b2f(kreg[i]));
    }
    if (tid < 256) {
      us vreg[8];
      *reinterpret_cast<uint4*>(vreg) = vr;
#pragma unroll
      for (int i = 0; i < 8; ++i) Vt[(vseg * 8 + i) * 72 + vrow] = f2b(betv * b2f(vreg[i]));
    }
    load_regs(c < 63 ? c + 1 : 63);
    __syncthreads();
    // ---------------- G1: Q.S0 (regs) + P + RHS ----------------
    int rtO = w >> 1, ctv = w & 1;
    f32x4 o1 = tile_range(Qb, 136, Sb, 136, rtO, ctv, 0, 4, lane, f32x4{});
    {
      int art = w & 3;
#pragma unroll
      for (int s = 0; s < 2; ++s) {
        int ct = (w >> 2) * 2 + s;
        f32x4 a = tile_range(Qb, 136, Kb, 136, art, ct, 0, 4, lane, f32x4{});
#pragma unroll
        for (int e = 0; e < 4; ++e) {
          int tr = art * 16 + (lane >> 4) * 4 + e;
          int cl = ct * 16 + (lane & 15);
          float pv = (cl <= tr) ? __expf(bl_s[tr] - bl_s[cl]) * a[e] : 0.f;
          WP[tr * 72 + cl] = f2b(pv);
        }
      }
    }
    {
      int vrt = w >> 2, ct = w & 3;
      f32x4 a = tile_range(Sb, 136, Kb, 136, vrt, ct, 0, 4, lane, f32x4{});
      int tt = ct * 16 + (lane & 15);
      float csc = bet_s[tt] * __expf(bl_s[tt]);
#pragma unroll
      for (int e = 0; e < 4; ++e) {
        int vv = vrt * 16 + (lane >> 4) * 4 + e;
        Vt[vv * 72 + tt] = f2b(b2f(Vt[vv * 72 + tt]) - csc * a[e]);
      }
    }
    __syncthreads();
    // ---------------- G2: Ut = RHS^T . T^T ----------------
    {
      int vrt = w >> 2, ct = w & 3;
      f32x4 a = tile_range(Vt, 72, W3, 72, vrt, ct, 0, 2, lane, f32x4{});
#pragma unroll
      for (int e = 0; e < 4; ++e)
        Ut[(vrt * 16 + (lane >> 4) * 4 + e) * 72 + ct * 16 + (lane & 15)] = f2b(a[e]);
    }
    __syncthreads();
    // ---------------- OS: O write + S update ----------------
    float lamC = __expf(bl_s[63]);
    {
      f32x4 a = tile_range(WP, 72, Ut, 72, rtO, ctv, 0, 2, lane, f32x4{});
#pragma unroll
      for (int e = 0; e < 4; ++e) {
        int tt = rtO * 16 + (lane >> 4) * 4 + e;
        int vv = vs * 32 + ctv * 16 + (lane & 15);
        float val = __expf(bl_s[tt]) * o1[e] + a[e];
        o[((bt0 + tt) * 32 + h) * 128 + vv] = f2b(val);
      }
    }
#pragma unroll
    for (int s = 0; s < 2; ++s) {
      int ti = w * 2 + s;
      int vrt = ti >> 3, dt = ti & 7;
      f32x4 a = tile_range(Ut, 72, Ktb, 72, vrt, dt, 0, 2, lane, f32x4{});
#pragma unroll
      for (int e = 0; e < 4; ++e) {
        int vv = vrt * 16 + (lane >> 4) * 4 + e, dd = dt * 16 + (lane & 15);
        Sb[vv * 136 + dd] = f2b(lamC * b2f(Sb[vv * 136 + dd]) + a[e]);
      }
    }
    __syncthreads();
  }
}

// ---------------- gated RMSNorm, in place (y over o) ----------------
__global__ __launch_bounds__(256) void rms_gate(us* oy,
    const us* __restrict__ z, const float* __restrict__ nw) {
  int wid = threadIdx.x >> 6, lane = threadIdx.x & 63;
  size_t base = ((size_t)blockIdx.x * 4 + wid) * 128;
  float o0 = b2f(oy[base + lane]), o1 = b2f(oy[base + lane + 64]);
  float ss = o0 * o0 + o1 * o1;
#pragma unroll
  for (int m = 1; m < 64; m <<= 1) ss += __shfl_xor(ss, m, 64);
  float r = rsqrtf(ss * (1.f / 128.f) + 1e-6f);
  float z0 = b2f(z[base + lane]), z1 = b2f(z[base + lane + 64]);
  z0 = z0 / (1.f + __expf(-z0));
  z1 = z1 / (1.f + __expf(-z1));
  oy[base + lane] = f2b(o0 * r * nw[lane] * z0);
  oy[base + lane + 64] = f2b(o1 * r * nw[lane + 64] * z1);
}

extern "C" void kernel_launch(void* const* d_in, const int* in_sizes, int n_in,
                              void* d_out, int out_size, void* d_ws, size_t ws_size,
                              hipStream_t stream) {
  const float* hs      = (const float*)d_in[0];
  const float* W_qkv   = (const float*)d_in[1];
  const float* W_z     = (const float*)d_in[2];
  const float* W_b     = (const float*)d_in[3];
  const float* W_a     = (const float*)d_in[4];
  const float* conv_w  = (const float*)d_in[5];
  const float* dt_bias = (const float*)d_in[6];
  const float* A_log   = (const float*)d_in[7];
  const float* norm_w  = (const float*)d_in[8];
  const float* W_out   = (const float*)d_in[9];
  float* out = (float*)d_out;

  char* ws = (char*)d_ws;
  const size_t MiB = 1u << 20;
  // layout (MiB), peak 228 (proven safe):
  //  0-2 ba | 2-3 bl | 3-4 bt | 4-12 wt(qkv chunk) / 4-36 Tg(scan) / 4-20 wt16(z,out)
  //  36-68 mixed \__ 36-100 o | 68-100 hs_bf0 | 100-132 q -> hs_bf1
  //  132-164 k | 164-228 v -> z
  float* ba_buf = (float*)(ws);
  float* bl_g   = (float*)(ws + 2 * MiB);
  float* bt_g   = (float*)(ws + 3 * MiB);
  us*    wt     = (us*)(ws + 4 * MiB);
  us*    Tg     = (us*)(ws + 4 * MiB);
  us*    mixed  = (us*)(ws + 36 * MiB);
  us*    o_buf  = (us*)(ws + 36 * MiB);
  us*    hs_bf0 = (us*)(ws + 68 * MiB);
  us*    q_buf  = (us*)(ws + 100 * MiB);
  us*    hs_bf1 = q_buf;
  us*    k_buf  = (us*)(ws + 132 * MiB);
  us*    v_buf  = (us*)(ws + 164 * MiB);
  us*    z_bf   = v_buf;

  cvt_f32_bf16<<<2048, 256, 0, stream>>>(hs, hs_bf0, (long)8192 * 2048 / 4);

  // qkv projection in 4 chunks of 2048 cols, each followed by its conv
  for (int c = 0; c < 4; ++c) {
    transpose_cvt<<<dim3(64, 64), 256, 0, stream>>>(W_qkv, wt, 2048, 2048, 8192, c * 2048, 0);
    gemm256<true><<<dim3(32, 8), 512, 0, stream>>>(hs_bf0, wt, mixed, 2048, 2048);
    const float* cwc = conv_w + (size_t)c * 2048 * 4;
    if (c == 0)      conv_chunk<0><<<8192, 256, 0, stream>>>(mixed, cwc, q_buf, 0);
    else if (c == 1) conv_chunk<1><<<8192, 256, 0, stream>>>(mixed, cwc, k_buf, 0);
    else if (c == 2) conv_chunk<2><<<8192, 256, 0, stream>>>(mixed, cwc, v_buf, 0);
    else             conv_chunk<2><<<8192, 256, 0, stream>>>(mixed, cwc, v_buf, 16);
  }
  // beta/a projections + gates (tiny N=64: 128^2 kernel)
  transpose_cvt<<<dim3(1, 64), 256, 0, stream>>>(W_b, wt, 2048, 32, 32, 0, 0);
  transpose_cvt<<<dim3(1, 64), 256, 0, stream>>>(W_a, wt, 2048, 32, 32, 0, 32);
  gemm_lds_f32<<<dim3(64, 1), 256, 0, stream>>>(hs_bf0, wt, ba_buf, 2048, 63, 64, 64);
  gates_cumsum<<<1024, 256, 0, stream>>>(ba_buf, dt_bias, A_log, bl_g, bt_g);
  // two-pass chunked delta-rule scan
  scan_p1<<<4096, 512, 0, stream>>>(k_buf, bl_g, bt_g, Tg);
  scan_p2<<<256, 512, 0, stream>>>(q_buf, k_buf, v_buf, bl_g, bt_g, Tg, o_buf);
  // z projection: full N=4096 in one dispatch (Tg dead; wt16 = 16 MiB)
  cvt_f32_bf16<<<2048, 256, 0, stream>>>(hs, hs_bf1, (long)8192 * 2048 / 4);
  transpose_cvt<<<dim3(128, 64), 256, 0, stream>>>(W_z, wt, 2048, 4096, 4096, 0, 0);
  gemm256<true><<<dim3(32, 16), 512, 0, stream>>>(hs_bf1, wt, z_bf, 2048, 4096);
  // gated RMSNorm in place: o -> y
  rms_gate<<<65536, 256, 0, stream>>>(o_buf, z_bf, norm_w);
  // output projection: full N=2048, K=4096
  transpose_cvt<<<dim3(64, 128), 256, 0, stream>>>(W_out, wt, 4096, 2048, 2048, 0, 0);
  gemm256<false><<<dim3(32, 8), 512, 0, stream>>>(o_buf, wt, out, 4096, 2048);
}